// Round 4
// baseline (348.323 us; speedup 1.0000x reference)
//
#include <hip/hip_runtime.h>

#define D_FEAT 32
#define RSH 6              // 64 nodes per range
#define RS_NODES 64
#define MAX_NR 2048        // max ranges supported by LDS arrays (N <= 131072)
#define NB_BIN 512         // binning blocks

// Pass A: per-block LDS histogram of edge chunk by range key. No global atomics.
__global__ void binA_kernel(const int* __restrict__ dst, unsigned* __restrict__ A,
                            int E, int NR, int chunk) {
    __shared__ unsigned cnt[MAX_NR];
    for (int i = threadIdx.x; i < NR; i += blockDim.x) cnt[i] = 0u;
    __syncthreads();
    int b = blockIdx.x;
    int lo = b * chunk;
    int hi = min(lo + chunk, E);
    if (lo < hi) {
        int nq = (hi - lo) >> 2;
        const int4* p = (const int4*)(dst + lo);
        for (int q = threadIdx.x; q < nq; q += blockDim.x) {
            int4 v = p[q];
            atomicAdd(&cnt[v.x >> RSH], 1u);
            atomicAdd(&cnt[v.y >> RSH], 1u);
            atomicAdd(&cnt[v.z >> RSH], 1u);
            atomicAdd(&cnt[v.w >> RSH], 1u);
        }
        for (int i = lo + (nq << 2) + threadIdx.x; i < hi; i += blockDim.x)
            atomicAdd(&cnt[dst[i] >> RSH], 1u);
    }
    __syncthreads();
    for (int i = threadIdx.x; i < NR; i += blockDim.x)
        A[(size_t)b * NR + i] = cnt[i];  // coalesced per-block row
}

// Scan 1: for each range r, exclusive-scan its per-block counts (column of A).
// blockDim.x must be NB_BIN.
__global__ void scanA_kernel(unsigned* __restrict__ A, unsigned* __restrict__ keytot, int NR) {
    __shared__ unsigned tmp[NB_BIN];
    int r = blockIdx.x;
    int t = threadIdx.x;
    unsigned v = A[(size_t)t * NR + r];
    tmp[t] = v;
    for (int off = 1; off < NB_BIN; off <<= 1) {
        __syncthreads();
        unsigned x = (t >= off) ? tmp[t - off] : 0u;
        __syncthreads();
        tmp[t] += x;
    }
    A[(size_t)t * NR + r] = tmp[t] - v;  // exclusive within range
    if (t == NB_BIN - 1) keytot[r] = tmp[t];
}

// Scan 2: exclusive scan of per-range totals -> rs[NR+1]. Single block, 1024 threads,
// handles NR <= 2048 via double-buffered Hillis-Steele over 2048 slots.
__global__ void scanR_kernel(const unsigned* __restrict__ keytot, unsigned* __restrict__ rs, int NR) {
    __shared__ unsigned a[2][2048];
    int t = threadIdx.x;  // 0..1023
    a[0][t]        = (t < NR)        ? keytot[t]        : 0u;
    a[0][t + 1024] = (t + 1024 < NR) ? keytot[t + 1024] : 0u;
    int pin = 0;
    for (int off = 1; off < 2048; off <<= 1) {
        __syncthreads();
        int po = pin ^ 1;
        #pragma unroll
        for (int k = 0; k < 2; k++) {
            int idx = t + k * 1024;
            unsigned x = a[pin][idx];
            if (idx >= off) x += a[pin][idx - off];
            a[po][idx] = x;
        }
        pin ^= 1;
    }
    __syncthreads();
    #pragma unroll
    for (int k = 0; k < 2; k++) {
        int idx = t + k * 1024;
        if (idx < NR) rs[idx] = idx ? a[pin][idx - 1] : 0u;
    }
    if (t == 0) rs[NR] = a[pin][2047];
}

// Pass B: place (src,dst) into range-grouped order via LDS cursors. No global atomics.
__global__ void binB_kernel(const int* __restrict__ src, const int* __restrict__ dst,
                            const unsigned* __restrict__ A, const unsigned* __restrict__ rs,
                            uint2* __restrict__ binned, int E, int NR, int chunk) {
    __shared__ unsigned cur[MAX_NR];
    int b = blockIdx.x;
    for (int i = threadIdx.x; i < NR; i += blockDim.x)
        cur[i] = rs[i] + A[(size_t)b * NR + i];
    __syncthreads();
    int lo = b * chunk;
    int hi = min(lo + chunk, E);
    if (lo >= hi) return;
    int nq = (hi - lo) >> 2;
    const int4* ps = (const int4*)(src + lo);
    const int4* pd = (const int4*)(dst + lo);
    for (int q = threadIdx.x; q < nq; q += blockDim.x) {
        int4 s = ps[q];
        int4 d = pd[q];
        unsigned p0 = atomicAdd(&cur[d.x >> RSH], 1u);
        binned[p0] = make_uint2((unsigned)s.x, (unsigned)d.x);
        unsigned p1 = atomicAdd(&cur[d.y >> RSH], 1u);
        binned[p1] = make_uint2((unsigned)s.y, (unsigned)d.y);
        unsigned p2 = atomicAdd(&cur[d.z >> RSH], 1u);
        binned[p2] = make_uint2((unsigned)s.z, (unsigned)d.z);
        unsigned p3 = atomicAdd(&cur[d.w >> RSH], 1u);
        binned[p3] = make_uint2((unsigned)s.w, (unsigned)d.w);
    }
    for (int i = lo + (nq << 2) + threadIdx.x; i < hi; i += blockDim.x) {
        unsigned p = atomicAdd(&cur[dst[i] >> RSH], 1u);
        binned[p] = make_uint2((unsigned)src[i], (unsigned)dst[i]);
    }
}

// inv[n] = rsqrt(1 + deg[n]) via per-range LDS count of binned dst. Covers all nodes.
__global__ void inv_kernel(const uint2* __restrict__ binned, const unsigned* __restrict__ rs,
                           float* __restrict__ inv, int N) {
    __shared__ unsigned cnt[RS_NODES];
    int r = blockIdx.x;
    if (threadIdx.x < RS_NODES) cnt[threadIdx.x] = 0u;
    __syncthreads();
    unsigned e0 = rs[r], e1 = rs[r + 1];
    for (unsigned e = e0 + threadIdx.x; e < e1; e += blockDim.x)
        atomicAdd(&cnt[binned[e].y & (RS_NODES - 1)], 1u);
    __syncthreads();
    if (threadIdx.x < RS_NODES) {
        int n = r * RS_NODES + threadIdx.x;
        if (n < N) inv[n] = rsqrtf(1.0f + (float)cnt[threadIdx.x]);
    }
}

// Fused gather: one block per 64-node range, 8 waves (512 thr). Half-wave per edge:
// lane d accumulates inv[src]*feat[src][d] into LDS acc[dst&63][d] (bank = d, conflict-free).
// Epilogue: out[n][d] = inv[n]*(acc + inv[n]*feat[n][d]), coalesced, self-loop fused.
__global__ void gatherG_kernel(const float* __restrict__ feat, const uint2* __restrict__ binned,
                               const unsigned* __restrict__ rs, const float* __restrict__ inv,
                               float* __restrict__ out, int N) {
    __shared__ float acc[RS_NODES * D_FEAT];  // 8 KB
    int r = blockIdx.x;
    for (int i = threadIdx.x; i < RS_NODES * D_FEAT; i += blockDim.x) acc[i] = 0.0f;
    __syncthreads();
    unsigned e0 = rs[r], e1 = rs[r + 1];
    int h = threadIdx.x >> 5;   // half-wave id, 0..15
    int d = threadIdx.x & 31;   // feature dim
    unsigned e = e0 + h;
    for (; e + 16 < e1; e += 32) {  // unroll 2 for load ILP
        uint2 ea = binned[e];
        uint2 eb = binned[e + 16];
        float va = inv[ea.x] * feat[(size_t)ea.x * D_FEAT + d];
        float vb = inv[eb.x] * feat[(size_t)eb.x * D_FEAT + d];
        atomicAdd(&acc[(ea.y & (RS_NODES - 1)) * D_FEAT + d], va);
        atomicAdd(&acc[(eb.y & (RS_NODES - 1)) * D_FEAT + d], vb);
    }
    for (; e < e1; e += 16) {
        uint2 ea = binned[e];
        atomicAdd(&acc[(ea.y & (RS_NODES - 1)) * D_FEAT + d],
                  inv[ea.x] * feat[(size_t)ea.x * D_FEAT + d]);
    }
    __syncthreads();
    int base = r * RS_NODES;
    for (int i = threadIdx.x; i < RS_NODES * D_FEAT; i += blockDim.x) {
        int n = base + (i >> 5);
        if (n < N) {
            float iv = inv[n];
            size_t o = (size_t)n * D_FEAT + (i & 31);
            out[o] = iv * (acc[i] + iv * feat[o]);
        }
    }
}

// ---------- fallback (atomic scatter) if workspace too small ----------

__global__ void fb_deg_kernel(const int* __restrict__ dst, float* __restrict__ deg, int E) {
    int i = blockIdx.x * blockDim.x + threadIdx.x;
    int stride = gridDim.x * blockDim.x;
    for (; i < E; i += stride) atomicAdd(&deg[dst[i]], 1.0f);
}
__global__ void fb_inv_kernel(const float* __restrict__ deg, float* __restrict__ inv, int N) {
    int i = blockIdx.x * blockDim.x + threadIdx.x;
    if (i < N) inv[i] = rsqrtf(1.0f + deg[i]);
}
__global__ void fb_scatter_kernel(const float* __restrict__ feat, const int* __restrict__ src,
                                  const int* __restrict__ dst, const float* __restrict__ inv,
                                  float* __restrict__ out, int E) {
    long long tid = (long long)blockIdx.x * blockDim.x + threadIdx.x;
    int e = (int)(tid >> 5);
    int d = (int)(tid & 31);
    if (e >= E) return;
    int s = src[e];
    int t = dst[e];
    atomicAdd(&out[t * D_FEAT + d], inv[s] * feat[s * D_FEAT + d]);
}
__global__ void fb_finalize_kernel(const float* __restrict__ feat, const float* __restrict__ inv,
                                   float* __restrict__ out, int ND) {
    int tid = blockIdx.x * blockDim.x + threadIdx.x;
    if (tid >= ND) return;
    float iv = inv[tid >> 5];
    out[tid] = iv * (out[tid] + iv * feat[tid]);
}

extern "C" void kernel_launch(void* const* d_in, const int* in_sizes, int n_in,
                              void* d_out, int out_size, void* d_ws, size_t ws_size,
                              hipStream_t stream) {
    const float* feat = (const float*)d_in[0];
    const int* esrc = (const int*)d_in[1];
    const int* edst = (const int*)d_in[2];
    float* out = (float*)d_out;

    const int N = in_sizes[0] / D_FEAT;
    const int E = in_sizes[1];
    const int ND = N * D_FEAT;
    const int NR = (N + RS_NODES - 1) >> RSH;
    const int chunk = (((E + NB_BIN - 1) / NB_BIN) + 3) & ~3;

    // ws words: binned(2E) + A(NR*NB) + keytot(NR) + rs(NR+1) + inv(N)
    size_t need = ((size_t)2 * E + (size_t)NR * NB_BIN + 2 * (size_t)NR + 1 + (size_t)N) * 4;
    if (ws_size >= need && NR <= MAX_NR) {
        unsigned* binned_u = (unsigned*)d_ws;
        unsigned* A        = binned_u + (size_t)2 * E;
        unsigned* keytot   = A + (size_t)NR * NB_BIN;
        unsigned* rs       = keytot + NR;
        float*    inv      = (float*)(rs + NR + 1);
        uint2*    binned   = (uint2*)binned_u;

        binA_kernel<<<NB_BIN, 256, 0, stream>>>(edst, A, E, NR, chunk);
        scanA_kernel<<<NR, NB_BIN, 0, stream>>>(A, keytot, NR);
        scanR_kernel<<<1, 1024, 0, stream>>>(keytot, rs, NR);
        binB_kernel<<<NB_BIN, 256, 0, stream>>>(esrc, edst, A, rs, binned, E, NR, chunk);
        inv_kernel<<<NR, 256, 0, stream>>>(binned, rs, inv, N);
        gatherG_kernel<<<NR, 512, 0, stream>>>(feat, binned, rs, inv, out, N);
    } else {
        float* deg = (float*)d_ws;
        float* inv = deg + N;
        hipMemsetAsync(deg, 0, (size_t)N * sizeof(float), stream);
        hipMemsetAsync(out, 0, (size_t)ND * sizeof(float), stream);
        {
            int grid = (E + 255) / 256; if (grid > 2048) grid = 2048;
            fb_deg_kernel<<<grid, 256, 0, stream>>>(edst, deg, E);
        }
        fb_inv_kernel<<<(N + 255) / 256, 256, 0, stream>>>(deg, inv, N);
        {
            long long total = (long long)E * D_FEAT;
            fb_scatter_kernel<<<(int)((total + 255) / 256), 256, 0, stream>>>(feat, esrc, edst, inv, out, E);
        }
        fb_finalize_kernel<<<(ND + 255) / 256, 256, 0, stream>>>(feat, inv, out, ND);
    }
}

// Round 5
// 109.151 us; speedup vs baseline: 3.1912x; 3.1912x over previous
//
#include <hip/hip_runtime.h>

#define D_FEAT 32
#define RSH 6              // 64 nodes per range
#define RS_NODES 64
#define MAX_NR 2048        // max ranges (N <= 131072)
#define NB_BIN 512         // binning blocks

// Pass A: per-block LDS histogram of edge chunk by range key (dst>>6). No global atomics.
__global__ void binA_kernel(const int* __restrict__ dst, unsigned* __restrict__ A,
                            int E, int NR, int chunk) {
    __shared__ unsigned cnt[MAX_NR];
    for (int i = threadIdx.x; i < NR; i += blockDim.x) cnt[i] = 0u;
    __syncthreads();
    int b = blockIdx.x;
    int lo = b * chunk;
    int hi = min(lo + chunk, E);
    if (lo < hi) {
        int nq = (hi - lo) >> 2;
        const int4* p = (const int4*)(dst + lo);
        for (int q = threadIdx.x; q < nq; q += blockDim.x) {
            int4 v = p[q];
            atomicAdd(&cnt[v.x >> RSH], 1u);
            atomicAdd(&cnt[v.y >> RSH], 1u);
            atomicAdd(&cnt[v.z >> RSH], 1u);
            atomicAdd(&cnt[v.w >> RSH], 1u);
        }
        for (int i = lo + (nq << 2) + threadIdx.x; i < hi; i += blockDim.x)
            atomicAdd(&cnt[dst[i] >> RSH], 1u);
    }
    __syncthreads();
    for (int i = threadIdx.x; i < NR; i += blockDim.x)
        A[(size_t)b * NR + i] = cnt[i];
}

// Scan 1: per range, exclusive-scan its per-block counts. blockDim.x == NB_BIN.
__global__ void scanA_kernel(unsigned* __restrict__ A, unsigned* __restrict__ keytot, int NR) {
    __shared__ unsigned tmp[NB_BIN];
    int r = blockIdx.x;
    int t = threadIdx.x;
    unsigned v = A[(size_t)t * NR + r];
    tmp[t] = v;
    for (int off = 1; off < NB_BIN; off <<= 1) {
        __syncthreads();
        unsigned x = (t >= off) ? tmp[t - off] : 0u;
        __syncthreads();
        tmp[t] += x;
    }
    A[(size_t)t * NR + r] = tmp[t] - v;
    if (t == NB_BIN - 1) keytot[r] = tmp[t];
}

// Scan 2: exclusive scan of per-range totals -> rs[NR+1]. NR <= 2048.
__global__ void scanR_kernel(const unsigned* __restrict__ keytot, unsigned* __restrict__ rs, int NR) {
    __shared__ unsigned a[2][2048];
    int t = threadIdx.x;  // 0..1023
    a[0][t]        = (t < NR)        ? keytot[t]        : 0u;
    a[0][t + 1024] = (t + 1024 < NR) ? keytot[t + 1024] : 0u;
    int pin = 0;
    for (int off = 1; off < 2048; off <<= 1) {
        __syncthreads();
        int po = pin ^ 1;
        #pragma unroll
        for (int k = 0; k < 2; k++) {
            int idx = t + k * 1024;
            unsigned x = a[pin][idx];
            if (idx >= off) x += a[pin][idx - off];
            a[po][idx] = x;
        }
        pin ^= 1;
    }
    __syncthreads();
    #pragma unroll
    for (int k = 0; k < 2; k++) {
        int idx = t + k * 1024;
        if (idx < NR) rs[idx] = idx ? a[pin][idx - 1] : 0u;
    }
    if (t == 0) rs[NR] = a[pin][2047];
}

// Pass B: place packed edge (src | (dst&63)<<26) into range-grouped order via LDS cursors.
__global__ void binB_kernel(const int* __restrict__ src, const int* __restrict__ dst,
                            const unsigned* __restrict__ A, const unsigned* __restrict__ rs,
                            unsigned* __restrict__ binned, int E, int NR, int chunk) {
    __shared__ unsigned cur[MAX_NR];
    int b = blockIdx.x;
    for (int i = threadIdx.x; i < NR; i += blockDim.x)
        cur[i] = rs[i] + A[(size_t)b * NR + i];
    __syncthreads();
    int lo = b * chunk;
    int hi = min(lo + chunk, E);
    if (lo >= hi) return;
    int nq = (hi - lo) >> 2;
    const int4* ps = (const int4*)(src + lo);
    const int4* pd = (const int4*)(dst + lo);
    for (int q = threadIdx.x; q < nq; q += blockDim.x) {
        int4 s = ps[q];
        int4 d = pd[q];
        unsigned p0 = atomicAdd(&cur[d.x >> RSH], 1u);
        binned[p0] = (unsigned)s.x | ((unsigned)(d.x & (RS_NODES - 1)) << 26);
        unsigned p1 = atomicAdd(&cur[d.y >> RSH], 1u);
        binned[p1] = (unsigned)s.y | ((unsigned)(d.y & (RS_NODES - 1)) << 26);
        unsigned p2 = atomicAdd(&cur[d.z >> RSH], 1u);
        binned[p2] = (unsigned)s.z | ((unsigned)(d.z & (RS_NODES - 1)) << 26);
        unsigned p3 = atomicAdd(&cur[d.w >> RSH], 1u);
        binned[p3] = (unsigned)s.w | ((unsigned)(d.w & (RS_NODES - 1)) << 26);
    }
    for (int i = lo + (nq << 2) + threadIdx.x; i < hi; i += blockDim.x) {
        unsigned p = atomicAdd(&cur[dst[i] >> RSH], 1u);
        binned[p] = (unsigned)src[i] | ((unsigned)(dst[i] & (RS_NODES - 1)) << 26);
    }
}

// Build exact per-node CSR within each range: count -> wave scan -> place.
// Also emits rowstart[node] and inv[node]. LDS u32 atomics only (O(E) lane-ops).
__global__ void build_kernel(const unsigned* __restrict__ binned, const unsigned* __restrict__ rs,
                             unsigned* __restrict__ csr, unsigned* __restrict__ rowstart,
                             float* __restrict__ inv, int N, int E) {
    __shared__ unsigned deg64[RS_NODES];
    __shared__ unsigned cur64[RS_NODES];
    int r = blockIdx.x;
    if (threadIdx.x < RS_NODES) deg64[threadIdx.x] = 0u;
    __syncthreads();
    unsigned e0 = rs[r], e1 = rs[r + 1];
    for (unsigned e = e0 + threadIdx.x; e < e1; e += blockDim.x)
        atomicAdd(&deg64[binned[e] >> 26], 1u);
    __syncthreads();
    if (threadIdx.x < RS_NODES) {  // wave 0 does the 64-wide scan
        unsigned d = deg64[threadIdx.x];
        unsigned incl = d;
        #pragma unroll
        for (int off = 1; off < RS_NODES; off <<= 1) {
            unsigned t = __shfl_up(incl, off, 64);
            if (threadIdx.x >= (unsigned)off) incl += t;
        }
        unsigned startpos = e0 + (incl - d);
        cur64[threadIdx.x] = startpos;
        int node = r * RS_NODES + threadIdx.x;
        if (node < N) {
            rowstart[node] = startpos;
            inv[node] = rsqrtf(1.0f + (float)d);
        }
    }
    if (r == 0 && threadIdx.x == 0) rowstart[N] = (unsigned)E;
    __syncthreads();
    for (unsigned e = e0 + threadIdx.x; e < e1; e += blockDim.x) {
        unsigned p = binned[e];
        unsigned pos = atomicAdd(&cur64[p >> 26], 1u);
        csr[pos] = p & 0x03FFFFFFu;
    }
}

// Wave per node: half-wave x unroll-4 -> 8 feat rows in flight; register accumulate;
// one shfl reduce; coalesced 128B store. Self-loop fused.
__global__ void gather_kernel(const float* __restrict__ feat, const unsigned* __restrict__ csr,
                              const unsigned* __restrict__ rowstart, const float* __restrict__ inv,
                              float* __restrict__ out, int N) {
    int wid = threadIdx.x >> 6;
    int node = blockIdx.x * (blockDim.x >> 6) + wid;
    if (node >= N) return;
    int lane = threadIdx.x & 63;
    int h = lane >> 5;
    int d = lane & 31;
    unsigned start = rowstart[node], end = rowstart[node + 1];
    float iv = inv[node];
    float acc = (h == 0) ? iv * feat[(size_t)node * D_FEAT + d] : 0.0f;
    unsigned k = start + h;
    for (; k + 6 < end; k += 8) {
        unsigned j0 = csr[k], j1 = csr[k + 2], j2 = csr[k + 4], j3 = csr[k + 6];
        float w0 = inv[j0], w1 = inv[j1], w2 = inv[j2], w3 = inv[j3];
        acc += w0 * feat[(size_t)j0 * D_FEAT + d];
        acc += w1 * feat[(size_t)j1 * D_FEAT + d];
        acc += w2 * feat[(size_t)j2 * D_FEAT + d];
        acc += w3 * feat[(size_t)j3 * D_FEAT + d];
    }
    for (; k < end; k += 2) {
        unsigned j = csr[k];
        acc += inv[j] * feat[(size_t)j * D_FEAT + d];
    }
    acc += __shfl_xor(acc, 32);
    if (h == 0) out[(size_t)node * D_FEAT + d] = iv * acc;
}

// ---------- fallback (atomic scatter) if workspace too small ----------

__global__ void fb_deg_kernel(const int* __restrict__ dst, float* __restrict__ deg, int E) {
    int i = blockIdx.x * blockDim.x + threadIdx.x;
    int stride = gridDim.x * blockDim.x;
    for (; i < E; i += stride) atomicAdd(&deg[dst[i]], 1.0f);
}
__global__ void fb_inv_kernel(const float* __restrict__ deg, float* __restrict__ inv, int N) {
    int i = blockIdx.x * blockDim.x + threadIdx.x;
    if (i < N) inv[i] = rsqrtf(1.0f + deg[i]);
}
__global__ void fb_scatter_kernel(const float* __restrict__ feat, const int* __restrict__ src,
                                  const int* __restrict__ dst, const float* __restrict__ inv,
                                  float* __restrict__ out, int E) {
    long long tid = (long long)blockIdx.x * blockDim.x + threadIdx.x;
    int e = (int)(tid >> 5);
    int d = (int)(tid & 31);
    if (e >= E) return;
    int s = src[e];
    int t = dst[e];
    atomicAdd(&out[t * D_FEAT + d], inv[s] * feat[s * D_FEAT + d]);
}
__global__ void fb_finalize_kernel(const float* __restrict__ feat, const float* __restrict__ inv,
                                   float* __restrict__ out, int ND) {
    int tid = blockIdx.x * blockDim.x + threadIdx.x;
    if (tid >= ND) return;
    float iv = inv[tid >> 5];
    out[tid] = iv * (out[tid] + iv * feat[tid]);
}

extern "C" void kernel_launch(void* const* d_in, const int* in_sizes, int n_in,
                              void* d_out, int out_size, void* d_ws, size_t ws_size,
                              hipStream_t stream) {
    const float* feat = (const float*)d_in[0];
    const int* esrc = (const int*)d_in[1];
    const int* edst = (const int*)d_in[2];
    float* out = (float*)d_out;

    const int N = in_sizes[0] / D_FEAT;
    const int E = in_sizes[1];
    const int ND = N * D_FEAT;
    const int NR = (N + RS_NODES - 1) >> RSH;
    const int chunk = (((E + NB_BIN - 1) / NB_BIN) + 3) & ~3;

    // ws words: binned(E) + csr(E) + A(NR*NB) + keytot(NR) + rs(NR+1) + rowstart(N+1) + inv(N)
    size_t need = ((size_t)2 * E + (size_t)NR * NB_BIN + 2 * (size_t)NR + 2 * (size_t)N + 2) * 4;
    if (ws_size >= need && NR <= MAX_NR && N <= (1 << 26)) {
        unsigned* binned   = (unsigned*)d_ws;
        unsigned* csr      = binned + E;
        unsigned* A        = csr + E;
        unsigned* keytot   = A + (size_t)NR * NB_BIN;
        unsigned* rs       = keytot + NR;
        unsigned* rowstart = rs + NR + 1;
        float*    inv      = (float*)(rowstart + N + 1);

        binA_kernel<<<NB_BIN, 256, 0, stream>>>(edst, A, E, NR, chunk);
        scanA_kernel<<<NR, NB_BIN, 0, stream>>>(A, keytot, NR);
        scanR_kernel<<<1, 1024, 0, stream>>>(keytot, rs, NR);
        binB_kernel<<<NB_BIN, 256, 0, stream>>>(esrc, edst, A, rs, binned, E, NR, chunk);
        build_kernel<<<NR, 256, 0, stream>>>(binned, rs, csr, rowstart, inv, N, E);
        {
            int waves_per_block = 4;  // 256 threads
            int grid = (N + waves_per_block - 1) / waves_per_block;
            gather_kernel<<<grid, 256, 0, stream>>>(feat, csr, rowstart, inv, out, N);
        }
    } else {
        float* deg = (float*)d_ws;
        float* inv = deg + N;
        hipMemsetAsync(deg, 0, (size_t)N * sizeof(float), stream);
        hipMemsetAsync(out, 0, (size_t)ND * sizeof(float), stream);
        {
            int grid = (E + 255) / 256; if (grid > 2048) grid = 2048;
            fb_deg_kernel<<<grid, 256, 0, stream>>>(edst, deg, E);
        }
        fb_inv_kernel<<<(N + 255) / 256, 256, 0, stream>>>(deg, inv, N);
        {
            long long total = (long long)E * D_FEAT;
            fb_scatter_kernel<<<(int)((total + 255) / 256), 256, 0, stream>>>(feat, esrc, edst, inv, out, E);
        }
        fb_finalize_kernel<<<(ND + 255) / 256, 256, 0, stream>>>(feat, inv, out, ND);
    }
}

// Round 6
// 95.584 us; speedup vs baseline: 3.6442x; 1.1419x over previous
//
#include <hip/hip_runtime.h>

#define D_FEAT 32
#define RSH 6              // 64 nodes per range
#define RS_NODES 64
#define MAX_NR 2048        // max ranges (N <= 131072)
#define NB_BIN 512         // binning blocks
#define SCANA_TR 16        // ranges per scanA block

// Pass A: per-block LDS histogram of edge chunk by range key (dst>>6). No global atomics.
__global__ void binA_kernel(const int* __restrict__ dst, unsigned* __restrict__ A,
                            int E, int NR, int chunk) {
    __shared__ unsigned cnt[MAX_NR];
    for (int i = threadIdx.x; i < NR; i += blockDim.x) cnt[i] = 0u;
    __syncthreads();
    int b = blockIdx.x;
    int lo = b * chunk;
    int hi = min(lo + chunk, E);
    if (lo < hi) {
        int nq = (hi - lo) >> 2;
        const int4* p = (const int4*)(dst + lo);
        for (int q = threadIdx.x; q < nq; q += blockDim.x) {
            int4 v = p[q];
            atomicAdd(&cnt[v.x >> RSH], 1u);
            atomicAdd(&cnt[v.y >> RSH], 1u);
            atomicAdd(&cnt[v.z >> RSH], 1u);
            atomicAdd(&cnt[v.w >> RSH], 1u);
        }
        for (int i = lo + (nq << 2) + threadIdx.x; i < hi; i += blockDim.x)
            atomicAdd(&cnt[dst[i] >> RSH], 1u);
    }
    __syncthreads();
    for (int i = threadIdx.x; i < NR; i += blockDim.x)
        A[(size_t)b * NR + i] = cnt[i];
}

// Scan 1 (tiled transpose): per block, stage 512 x SCANA_TR tile of A through LDS
// (coalesced rows), 8 waves shfl-scan the 512-deep bin dimension of 2 ranges each.
// Writes exclusive offsets back (same layout) and per-range totals.
__global__ void scanA_kernel(unsigned* __restrict__ A, unsigned* __restrict__ keytot, int NR) {
    __shared__ unsigned lds[SCANA_TR * 514];  // pad 514 -> 2-way bank alias only
    int r0 = blockIdx.x * SCANA_TR;
    int tid = threadIdx.x;  // 512 threads
    // load: consecutive tid -> consecutive global addresses (16-word runs)
    for (int idx = tid; idx < NB_BIN * SCANA_TR; idx += 512) {
        int c = idx & (SCANA_TR - 1);
        int b = idx >> 4;
        int r = r0 + c;
        lds[c * 514 + b] = (r < NR) ? A[(size_t)b * NR + r] : 0u;
    }
    __syncthreads();
    int wid = tid >> 6;
    int lane = tid & 63;
    #pragma unroll
    for (int cc = 0; cc < 2; cc++) {
        int c = wid * 2 + cc;
        unsigned carry = 0u;
        #pragma unroll
        for (int chunk = 0; chunk < NB_BIN / 64; chunk++) {
            unsigned v = lds[c * 514 + chunk * 64 + lane];
            unsigned incl = v;
            #pragma unroll
            for (int off = 1; off < 64; off <<= 1) {
                unsigned t = __shfl_up(incl, off, 64);
                if (lane >= off) incl += t;
            }
            lds[c * 514 + chunk * 64 + lane] = carry + incl - v;  // exclusive
            carry += __shfl(incl, 63, 64);
        }
        if (lane == 0 && (r0 + c) < NR) keytot[r0 + c] = carry;
    }
    __syncthreads();
    for (int idx = tid; idx < NB_BIN * SCANA_TR; idx += 512) {
        int c = idx & (SCANA_TR - 1);
        int b = idx >> 4;
        int r = r0 + c;
        if (r < NR) A[(size_t)b * NR + r] = lds[c * 514 + b];
    }
}

// Scan 2: exclusive scan of per-range totals -> rs[NR+1]. NR <= 2048.
__global__ void scanR_kernel(const unsigned* __restrict__ keytot, unsigned* __restrict__ rs, int NR) {
    __shared__ unsigned a[2][2048];
    int t = threadIdx.x;  // 0..1023
    a[0][t]        = (t < NR)        ? keytot[t]        : 0u;
    a[0][t + 1024] = (t + 1024 < NR) ? keytot[t + 1024] : 0u;
    int pin = 0;
    for (int off = 1; off < 2048; off <<= 1) {
        __syncthreads();
        int po = pin ^ 1;
        #pragma unroll
        for (int k = 0; k < 2; k++) {
            int idx = t + k * 1024;
            unsigned x = a[pin][idx];
            if (idx >= off) x += a[pin][idx - off];
            a[po][idx] = x;
        }
        pin ^= 1;
    }
    __syncthreads();
    #pragma unroll
    for (int k = 0; k < 2; k++) {
        int idx = t + k * 1024;
        if (idx < NR) rs[idx] = idx ? a[pin][idx - 1] : 0u;
    }
    if (t == 0) rs[NR] = a[pin][2047];
}

// Pass B: place packed edge (src | (dst&63)<<26) into range-grouped order via LDS cursors.
__global__ void binB_kernel(const int* __restrict__ src, const int* __restrict__ dst,
                            const unsigned* __restrict__ A, const unsigned* __restrict__ rs,
                            unsigned* __restrict__ binned, int E, int NR, int chunk) {
    __shared__ unsigned cur[MAX_NR];
    int b = blockIdx.x;
    for (int i = threadIdx.x; i < NR; i += blockDim.x)
        cur[i] = rs[i] + A[(size_t)b * NR + i];
    __syncthreads();
    int lo = b * chunk;
    int hi = min(lo + chunk, E);
    if (lo >= hi) return;
    int nq = (hi - lo) >> 2;
    const int4* ps = (const int4*)(src + lo);
    const int4* pd = (const int4*)(dst + lo);
    for (int q = threadIdx.x; q < nq; q += blockDim.x) {
        int4 s = ps[q];
        int4 d = pd[q];
        unsigned p0 = atomicAdd(&cur[d.x >> RSH], 1u);
        binned[p0] = (unsigned)s.x | ((unsigned)(d.x & (RS_NODES - 1)) << 26);
        unsigned p1 = atomicAdd(&cur[d.y >> RSH], 1u);
        binned[p1] = (unsigned)s.y | ((unsigned)(d.y & (RS_NODES - 1)) << 26);
        unsigned p2 = atomicAdd(&cur[d.z >> RSH], 1u);
        binned[p2] = (unsigned)s.z | ((unsigned)(d.z & (RS_NODES - 1)) << 26);
        unsigned p3 = atomicAdd(&cur[d.w >> RSH], 1u);
        binned[p3] = (unsigned)s.w | ((unsigned)(d.w & (RS_NODES - 1)) << 26);
    }
    for (int i = lo + (nq << 2) + threadIdx.x; i < hi; i += blockDim.x) {
        unsigned p = atomicAdd(&cur[dst[i] >> RSH], 1u);
        binned[p] = (unsigned)src[i] | ((unsigned)(dst[i] & (RS_NODES - 1)) << 26);
    }
}

// Build exact per-node CSR within each range: count -> wave scan -> place.
__global__ void build_kernel(const unsigned* __restrict__ binned, const unsigned* __restrict__ rs,
                             unsigned* __restrict__ csr, unsigned* __restrict__ rowstart,
                             float* __restrict__ inv, int N, int E) {
    __shared__ unsigned deg64[RS_NODES];
    __shared__ unsigned cur64[RS_NODES];
    int r = blockIdx.x;
    if (threadIdx.x < RS_NODES) deg64[threadIdx.x] = 0u;
    __syncthreads();
    unsigned e0 = rs[r], e1 = rs[r + 1];
    for (unsigned e = e0 + threadIdx.x; e < e1; e += blockDim.x)
        atomicAdd(&deg64[binned[e] >> 26], 1u);
    __syncthreads();
    if (threadIdx.x < RS_NODES) {
        unsigned d = deg64[threadIdx.x];
        unsigned incl = d;
        #pragma unroll
        for (int off = 1; off < RS_NODES; off <<= 1) {
            unsigned t = __shfl_up(incl, off, 64);
            if (threadIdx.x >= (unsigned)off) incl += t;
        }
        unsigned startpos = e0 + (incl - d);
        cur64[threadIdx.x] = startpos;
        int node = r * RS_NODES + threadIdx.x;
        if (node < N) {
            rowstart[node] = startpos;
            inv[node] = rsqrtf(1.0f + (float)d);
        }
    }
    if (r == 0 && threadIdx.x == 0) rowstart[N] = (unsigned)E;
    __syncthreads();
    for (unsigned e = e0 + threadIdx.x; e < e1; e += blockDim.x) {
        unsigned p = binned[e];
        unsigned pos = atomicAdd(&cur64[p >> 26], 1u);
        csr[pos] = p & 0x03FFFFFFu;
    }
}

// Gather: wave per node; 8 groups x 8 lanes; each lane covers 4 dims via float4.
// One feat-load instruction covers 8 random rows (8x MLP); 12-shfl group reduce.
__global__ void gather_kernel(const float* __restrict__ feat, const unsigned* __restrict__ csr,
                              const unsigned* __restrict__ rowstart, const float* __restrict__ inv,
                              float* __restrict__ out, int N) {
    int wid = threadIdx.x >> 6;
    int node = blockIdx.x * (blockDim.x >> 6) + wid;
    if (node >= N) return;
    int lane = threadIdx.x & 63;
    int g = lane >> 3;   // edge slot within iteration
    int q = lane & 7;    // float4 slot: dims [4q, 4q+4)
    unsigned start = rowstart[node], end = rowstart[node + 1];
    float iv = inv[node];
    float4 acc = make_float4(0.f, 0.f, 0.f, 0.f);
    if (g == 0) {  // self-loop: iv * feat[node] (scaled by iv again at store)
        float4 f = *(const float4*)(feat + (size_t)node * D_FEAT + q * 4);
        acc.x = iv * f.x; acc.y = iv * f.y; acc.z = iv * f.z; acc.w = iv * f.w;
    }
    unsigned k = start + g;
    for (; k + 8 < end; k += 16) {  // 2 edges per group in flight
        unsigned j0 = csr[k], j1 = csr[k + 8];
        float w0 = inv[j0], w1 = inv[j1];
        float4 f0 = *(const float4*)(feat + (size_t)j0 * D_FEAT + q * 4);
        float4 f1 = *(const float4*)(feat + (size_t)j1 * D_FEAT + q * 4);
        acc.x = fmaf(w0, f0.x, acc.x); acc.y = fmaf(w0, f0.y, acc.y);
        acc.z = fmaf(w0, f0.z, acc.z); acc.w = fmaf(w0, f0.w, acc.w);
        acc.x = fmaf(w1, f1.x, acc.x); acc.y = fmaf(w1, f1.y, acc.y);
        acc.z = fmaf(w1, f1.z, acc.z); acc.w = fmaf(w1, f1.w, acc.w);
    }
    if (k < end) {
        unsigned j = csr[k];
        float w = inv[j];
        float4 f = *(const float4*)(feat + (size_t)j * D_FEAT + q * 4);
        acc.x = fmaf(w, f.x, acc.x); acc.y = fmaf(w, f.y, acc.y);
        acc.z = fmaf(w, f.z, acc.z); acc.w = fmaf(w, f.w, acc.w);
    }
    #pragma unroll
    for (int off = 8; off < 64; off <<= 1) {
        acc.x += __shfl_xor(acc.x, off);
        acc.y += __shfl_xor(acc.y, off);
        acc.z += __shfl_xor(acc.z, off);
        acc.w += __shfl_xor(acc.w, off);
    }
    if (g == 0) {
        float4 r;
        r.x = iv * acc.x; r.y = iv * acc.y; r.z = iv * acc.z; r.w = iv * acc.w;
        *(float4*)(out + (size_t)node * D_FEAT + q * 4) = r;
    }
}

// ---------- fallback (atomic scatter) if workspace too small ----------

__global__ void fb_deg_kernel(const int* __restrict__ dst, float* __restrict__ deg, int E) {
    int i = blockIdx.x * blockDim.x + threadIdx.x;
    int stride = gridDim.x * blockDim.x;
    for (; i < E; i += stride) atomicAdd(&deg[dst[i]], 1.0f);
}
__global__ void fb_inv_kernel(const float* __restrict__ deg, float* __restrict__ inv, int N) {
    int i = blockIdx.x * blockDim.x + threadIdx.x;
    if (i < N) inv[i] = rsqrtf(1.0f + deg[i]);
}
__global__ void fb_scatter_kernel(const float* __restrict__ feat, const int* __restrict__ src,
                                  const int* __restrict__ dst, const float* __restrict__ inv,
                                  float* __restrict__ out, int E) {
    long long tid = (long long)blockIdx.x * blockDim.x + threadIdx.x;
    int e = (int)(tid >> 5);
    int d = (int)(tid & 31);
    if (e >= E) return;
    int s = src[e];
    int t = dst[e];
    atomicAdd(&out[t * D_FEAT + d], inv[s] * feat[s * D_FEAT + d]);
}
__global__ void fb_finalize_kernel(const float* __restrict__ feat, const float* __restrict__ inv,
                                   float* __restrict__ out, int ND) {
    int tid = blockIdx.x * blockDim.x + threadIdx.x;
    if (tid >= ND) return;
    float iv = inv[tid >> 5];
    out[tid] = iv * (out[tid] + iv * feat[tid]);
}

extern "C" void kernel_launch(void* const* d_in, const int* in_sizes, int n_in,
                              void* d_out, int out_size, void* d_ws, size_t ws_size,
                              hipStream_t stream) {
    const float* feat = (const float*)d_in[0];
    const int* esrc = (const int*)d_in[1];
    const int* edst = (const int*)d_in[2];
    float* out = (float*)d_out;

    const int N = in_sizes[0] / D_FEAT;
    const int E = in_sizes[1];
    const int ND = N * D_FEAT;
    const int NR = (N + RS_NODES - 1) >> RSH;
    const int chunk = (((E + NB_BIN - 1) / NB_BIN) + 3) & ~3;

    size_t need = ((size_t)2 * E + (size_t)NR * NB_BIN + 2 * (size_t)NR + 2 * (size_t)N + 2) * 4;
    if (ws_size >= need && NR <= MAX_NR && N <= (1 << 26)) {
        unsigned* binned   = (unsigned*)d_ws;
        unsigned* csr      = binned + E;
        unsigned* A        = csr + E;
        unsigned* keytot   = A + (size_t)NR * NB_BIN;
        unsigned* rs       = keytot + NR;
        unsigned* rowstart = rs + NR + 1;
        float*    inv      = (float*)(rowstart + N + 1);

        binA_kernel<<<NB_BIN, 256, 0, stream>>>(edst, A, E, NR, chunk);
        scanA_kernel<<<(NR + SCANA_TR - 1) / SCANA_TR, 512, 0, stream>>>(A, keytot, NR);
        scanR_kernel<<<1, 1024, 0, stream>>>(keytot, rs, NR);
        binB_kernel<<<NB_BIN, 256, 0, stream>>>(esrc, edst, A, rs, binned, E, NR, chunk);
        build_kernel<<<NR, 256, 0, stream>>>(binned, rs, csr, rowstart, inv, N, E);
        {
            int waves_per_block = 4;  // 256 threads
            int grid = (N + waves_per_block - 1) / waves_per_block;
            gather_kernel<<<grid, 256, 0, stream>>>(feat, csr, rowstart, inv, out, N);
        }
    } else {
        float* deg = (float*)d_ws;
        float* inv = deg + N;
        hipMemsetAsync(deg, 0, (size_t)N * sizeof(float), stream);
        hipMemsetAsync(out, 0, (size_t)ND * sizeof(float), stream);
        {
            int grid = (E + 255) / 256; if (grid > 2048) grid = 2048;
            fb_deg_kernel<<<grid, 256, 0, stream>>>(edst, deg, E);
        }
        fb_inv_kernel<<<(N + 255) / 256, 256, 0, stream>>>(deg, inv, N);
        {
            long long total = (long long)E * D_FEAT;
            fb_scatter_kernel<<<(int)((total + 255) / 256), 256, 0, stream>>>(feat, esrc, edst, inv, out, E);
        }
        fb_finalize_kernel<<<(ND + 255) / 256, 256, 0, stream>>>(feat, inv, out, ND);
    }
}

// Round 7
// 94.728 us; speedup vs baseline: 3.6771x; 1.0090x over previous
//
#include <hip/hip_runtime.h>

#define D_FEAT 32
#define RSH 6              // 64 nodes per range
#define RS_NODES 64
#define MAX_NR 2048        // max ranges (N <= 131072)
#define NB_BIN 512         // binning blocks
#define SCANA_TR 16        // ranges per scanA block

// round-to-nearest-even bf16 pack of two floats
__device__ __forceinline__ unsigned bfpack(float lo, float hi) {
    unsigned ul = __float_as_uint(lo), uh = __float_as_uint(hi);
    ul = (ul + 0x7FFFu + ((ul >> 16) & 1u)) >> 16;
    uh = (uh + 0x7FFFu + ((uh >> 16) & 1u)) >> 16;
    return ul | (uh << 16);
}

// Pass A: per-block LDS histogram of edge chunk by range key (dst>>6). No global atomics.
__global__ void binA_kernel(const int* __restrict__ dst, unsigned* __restrict__ A,
                            int E, int NR, int chunk) {
    __shared__ unsigned cnt[MAX_NR];
    for (int i = threadIdx.x; i < NR; i += blockDim.x) cnt[i] = 0u;
    __syncthreads();
    int b = blockIdx.x;
    int lo = b * chunk;
    int hi = min(lo + chunk, E);
    if (lo < hi) {
        int nq = (hi - lo) >> 2;
        const int4* p = (const int4*)(dst + lo);
        for (int q = threadIdx.x; q < nq; q += blockDim.x) {
            int4 v = p[q];
            atomicAdd(&cnt[v.x >> RSH], 1u);
            atomicAdd(&cnt[v.y >> RSH], 1u);
            atomicAdd(&cnt[v.z >> RSH], 1u);
            atomicAdd(&cnt[v.w >> RSH], 1u);
        }
        for (int i = lo + (nq << 2) + threadIdx.x; i < hi; i += blockDim.x)
            atomicAdd(&cnt[dst[i] >> RSH], 1u);
    }
    __syncthreads();
    for (int i = threadIdx.x; i < NR; i += blockDim.x)
        A[(size_t)b * NR + i] = cnt[i];
}

// Scan 1 (tiled transpose): stage 512 x SCANA_TR tile through LDS, shfl-scan bins.
__global__ void scanA_kernel(unsigned* __restrict__ A, unsigned* __restrict__ keytot, int NR) {
    __shared__ unsigned lds[SCANA_TR * 514];
    int r0 = blockIdx.x * SCANA_TR;
    int tid = threadIdx.x;  // 512 threads
    for (int idx = tid; idx < NB_BIN * SCANA_TR; idx += 512) {
        int c = idx & (SCANA_TR - 1);
        int b = idx >> 4;
        int r = r0 + c;
        lds[c * 514 + b] = (r < NR) ? A[(size_t)b * NR + r] : 0u;
    }
    __syncthreads();
    int wid = tid >> 6;
    int lane = tid & 63;
    #pragma unroll
    for (int cc = 0; cc < 2; cc++) {
        int c = wid * 2 + cc;
        unsigned carry = 0u;
        #pragma unroll
        for (int chunk = 0; chunk < NB_BIN / 64; chunk++) {
            unsigned v = lds[c * 514 + chunk * 64 + lane];
            unsigned incl = v;
            #pragma unroll
            for (int off = 1; off < 64; off <<= 1) {
                unsigned t = __shfl_up(incl, off, 64);
                if (lane >= off) incl += t;
            }
            lds[c * 514 + chunk * 64 + lane] = carry + incl - v;
            carry += __shfl(incl, 63, 64);
        }
        if (lane == 0 && (r0 + c) < NR) keytot[r0 + c] = carry;
    }
    __syncthreads();
    for (int idx = tid; idx < NB_BIN * SCANA_TR; idx += 512) {
        int c = idx & (SCANA_TR - 1);
        int b = idx >> 4;
        int r = r0 + c;
        if (r < NR) A[(size_t)b * NR + r] = lds[c * 514 + b];
    }
}

// Scan 2: exclusive scan of per-range totals -> rs[NR+1]. NR <= 2048.
__global__ void scanR_kernel(const unsigned* __restrict__ keytot, unsigned* __restrict__ rs, int NR) {
    __shared__ unsigned a[2][2048];
    int t = threadIdx.x;
    a[0][t]        = (t < NR)        ? keytot[t]        : 0u;
    a[0][t + 1024] = (t + 1024 < NR) ? keytot[t + 1024] : 0u;
    int pin = 0;
    for (int off = 1; off < 2048; off <<= 1) {
        __syncthreads();
        int po = pin ^ 1;
        #pragma unroll
        for (int k = 0; k < 2; k++) {
            int idx = t + k * 1024;
            unsigned x = a[pin][idx];
            if (idx >= off) x += a[pin][idx - off];
            a[po][idx] = x;
        }
        pin ^= 1;
    }
    __syncthreads();
    #pragma unroll
    for (int k = 0; k < 2; k++) {
        int idx = t + k * 1024;
        if (idx < NR) rs[idx] = idx ? a[pin][idx - 1] : 0u;
    }
    if (t == 0) rs[NR] = a[pin][2047];
}

// Pass B: place packed edge (src | (dst&63)<<26) into range-grouped order via LDS cursors.
__global__ void binB_kernel(const int* __restrict__ src, const int* __restrict__ dst,
                            const unsigned* __restrict__ A, const unsigned* __restrict__ rs,
                            unsigned* __restrict__ binned, int E, int NR, int chunk) {
    __shared__ unsigned cur[MAX_NR];
    int b = blockIdx.x;
    for (int i = threadIdx.x; i < NR; i += blockDim.x)
        cur[i] = rs[i] + A[(size_t)b * NR + i];
    __syncthreads();
    int lo = b * chunk;
    int hi = min(lo + chunk, E);
    if (lo >= hi) return;
    int nq = (hi - lo) >> 2;
    const int4* ps = (const int4*)(src + lo);
    const int4* pd = (const int4*)(dst + lo);
    for (int q = threadIdx.x; q < nq; q += blockDim.x) {
        int4 s = ps[q];
        int4 d = pd[q];
        unsigned p0 = atomicAdd(&cur[d.x >> RSH], 1u);
        binned[p0] = (unsigned)s.x | ((unsigned)(d.x & (RS_NODES - 1)) << 26);
        unsigned p1 = atomicAdd(&cur[d.y >> RSH], 1u);
        binned[p1] = (unsigned)s.y | ((unsigned)(d.y & (RS_NODES - 1)) << 26);
        unsigned p2 = atomicAdd(&cur[d.z >> RSH], 1u);
        binned[p2] = (unsigned)s.z | ((unsigned)(d.z & (RS_NODES - 1)) << 26);
        unsigned p3 = atomicAdd(&cur[d.w >> RSH], 1u);
        binned[p3] = (unsigned)s.w | ((unsigned)(d.w & (RS_NODES - 1)) << 26);
    }
    for (int i = lo + (nq << 2) + threadIdx.x; i < hi; i += blockDim.x) {
        unsigned p = atomicAdd(&cur[dst[i] >> RSH], 1u);
        binned[p] = (unsigned)src[i] | ((unsigned)(dst[i] & (RS_NODES - 1)) << 26);
    }
}

// Build per-node CSR within each range (count -> wave scan -> place) AND convert the
// range's 64 feature rows to pre-scaled bf16: wf[n] = bf16(inv[n]*feat[n]), 64 B/row.
__global__ void build_kernel(const unsigned* __restrict__ binned, const unsigned* __restrict__ rs,
                             const float* __restrict__ feat, unsigned* __restrict__ wf,
                             unsigned* __restrict__ csr, unsigned* __restrict__ rowstart,
                             float* __restrict__ inv, int N, int E) {
    __shared__ unsigned deg64[RS_NODES];
    __shared__ unsigned cur64[RS_NODES];
    __shared__ float sinv[RS_NODES];
    int r = blockIdx.x;
    if (threadIdx.x < RS_NODES) deg64[threadIdx.x] = 0u;
    __syncthreads();
    unsigned e0 = rs[r], e1 = rs[r + 1];
    for (unsigned e = e0 + threadIdx.x; e < e1; e += blockDim.x)
        atomicAdd(&deg64[binned[e] >> 26], 1u);
    __syncthreads();
    if (threadIdx.x < RS_NODES) {
        unsigned d = deg64[threadIdx.x];
        unsigned incl = d;
        #pragma unroll
        for (int off = 1; off < RS_NODES; off <<= 1) {
            unsigned t = __shfl_up(incl, off, 64);
            if (threadIdx.x >= (unsigned)off) incl += t;
        }
        unsigned startpos = e0 + (incl - d);
        cur64[threadIdx.x] = startpos;
        float ivv = rsqrtf(1.0f + (float)d);
        sinv[threadIdx.x] = ivv;
        int node = r * RS_NODES + threadIdx.x;
        if (node < N) {
            rowstart[node] = startpos;
            inv[node] = ivv;
        }
    }
    if (r == 0 && threadIdx.x == 0) rowstart[N] = (unsigned)E;
    __syncthreads();
    // place edges into exact per-node CSR
    for (unsigned e = e0 + threadIdx.x; e < e1; e += blockDim.x) {
        unsigned p = binned[e];
        unsigned pos = atomicAdd(&cur64[p >> 26], 1u);
        csr[pos] = p & 0x03FFFFFFu;
    }
    // convert 64 rows: thread t handles node r*64+(t>>2), dims [8*(t&3), 8*(t&3)+8)
    {
        int nl = threadIdx.x >> 2;
        int q = threadIdx.x & 3;
        int node = r * RS_NODES + nl;
        if (node < N) {
            float ivv = sinv[nl];
            const float4* fp = (const float4*)(feat + (size_t)node * D_FEAT + q * 8);
            float4 a = fp[0];
            float4 b = fp[1];
            uint4 o;
            o.x = bfpack(ivv * a.x, ivv * a.y);
            o.y = bfpack(ivv * a.z, ivv * a.w);
            o.z = bfpack(ivv * b.x, ivv * b.y);
            o.w = bfpack(ivv * b.z, ivv * b.w);
            ((uint4*)wf)[(size_t)node * 4 + q] = o;
        }
    }
}

// Gather: wave per node; 8 groups x 8 lanes; lane q covers dims [4q,4q+4) via one
// uint2 (4 bf16) per edge -> ONE 64B line per edge row. fp32 accumulate; 12-shfl reduce.
__global__ void gather_kernel(const float* __restrict__ feat, const unsigned* __restrict__ wf,
                              const unsigned* __restrict__ csr, const unsigned* __restrict__ rowstart,
                              const float* __restrict__ inv, float* __restrict__ out, int N) {
    int wid = threadIdx.x >> 6;
    int node = blockIdx.x * (blockDim.x >> 6) + wid;
    if (node >= N) return;
    int lane = threadIdx.x & 63;
    int g = lane >> 3;   // edge slot within iteration
    int q = lane & 7;    // dim quad: [4q, 4q+4)
    unsigned start = rowstart[node], end = rowstart[node + 1];
    float iv = inv[node];
    float4 acc = make_float4(0.f, 0.f, 0.f, 0.f);
    if (g == 0) {  // self-loop in fp32: iv * feat[node] (scaled by iv again at store)
        float4 f = *(const float4*)(feat + (size_t)node * D_FEAT + q * 4);
        acc.x = iv * f.x; acc.y = iv * f.y; acc.z = iv * f.z; acc.w = iv * f.w;
    }
    unsigned k = start + g;
    for (; k + 8 < end; k += 16) {
        unsigned j0 = csr[k], j1 = csr[k + 8];
        uint2 w0 = *(const uint2*)(wf + (size_t)j0 * 16 + q * 2);
        uint2 w1 = *(const uint2*)(wf + (size_t)j1 * 16 + q * 2);
        acc.x += __uint_as_float(w0.x << 16);
        acc.y += __uint_as_float(w0.x & 0xFFFF0000u);
        acc.z += __uint_as_float(w0.y << 16);
        acc.w += __uint_as_float(w0.y & 0xFFFF0000u);
        acc.x += __uint_as_float(w1.x << 16);
        acc.y += __uint_as_float(w1.x & 0xFFFF0000u);
        acc.z += __uint_as_float(w1.y << 16);
        acc.w += __uint_as_float(w1.y & 0xFFFF0000u);
    }
    if (k < end) {
        unsigned j = csr[k];
        uint2 w = *(const uint2*)(wf + (size_t)j * 16 + q * 2);
        acc.x += __uint_as_float(w.x << 16);
        acc.y += __uint_as_float(w.x & 0xFFFF0000u);
        acc.z += __uint_as_float(w.y << 16);
        acc.w += __uint_as_float(w.y & 0xFFFF0000u);
    }
    #pragma unroll
    for (int off = 8; off < 64; off <<= 1) {
        acc.x += __shfl_xor(acc.x, off);
        acc.y += __shfl_xor(acc.y, off);
        acc.z += __shfl_xor(acc.z, off);
        acc.w += __shfl_xor(acc.w, off);
    }
    if (g == 0) {
        float4 rv;
        rv.x = iv * acc.x; rv.y = iv * acc.y; rv.z = iv * acc.z; rv.w = iv * acc.w;
        *(float4*)(out + (size_t)node * D_FEAT + q * 4) = rv;
    }
}

// ---------- fallback (atomic scatter) if workspace too small ----------

__global__ void fb_deg_kernel(const int* __restrict__ dst, float* __restrict__ deg, int E) {
    int i = blockIdx.x * blockDim.x + threadIdx.x;
    int stride = gridDim.x * blockDim.x;
    for (; i < E; i += stride) atomicAdd(&deg[dst[i]], 1.0f);
}
__global__ void fb_inv_kernel(const float* __restrict__ deg, float* __restrict__ inv, int N) {
    int i = blockIdx.x * blockDim.x + threadIdx.x;
    if (i < N) inv[i] = rsqrtf(1.0f + deg[i]);
}
__global__ void fb_scatter_kernel(const float* __restrict__ feat, const int* __restrict__ src,
                                  const int* __restrict__ dst, const float* __restrict__ inv,
                                  float* __restrict__ out, int E) {
    long long tid = (long long)blockIdx.x * blockDim.x + threadIdx.x;
    int e = (int)(tid >> 5);
    int d = (int)(tid & 31);
    if (e >= E) return;
    int s = src[e];
    int t = dst[e];
    atomicAdd(&out[t * D_FEAT + d], inv[s] * feat[s * D_FEAT + d]);
}
__global__ void fb_finalize_kernel(const float* __restrict__ feat, const float* __restrict__ inv,
                                   float* __restrict__ out, int ND) {
    int tid = blockIdx.x * blockDim.x + threadIdx.x;
    if (tid >= ND) return;
    float iv = inv[tid >> 5];
    out[tid] = iv * (out[tid] + iv * feat[tid]);
}

extern "C" void kernel_launch(void* const* d_in, const int* in_sizes, int n_in,
                              void* d_out, int out_size, void* d_ws, size_t ws_size,
                              hipStream_t stream) {
    const float* feat = (const float*)d_in[0];
    const int* esrc = (const int*)d_in[1];
    const int* edst = (const int*)d_in[2];
    float* out = (float*)d_out;

    const int N = in_sizes[0] / D_FEAT;
    const int E = in_sizes[1];
    const int ND = N * D_FEAT;
    const int NR = (N + RS_NODES - 1) >> RSH;
    const int chunk = (((E + NB_BIN - 1) / NB_BIN) + 3) & ~3;

    // words: binned(E) + csr(E) + wf(16N, 16B-aligned) + A(NR*NB) + keytot(NR) + rs(NR+1)
    //        + rowstart(N+1) + inv(N)
    size_t wf_off = ((size_t)2 * E + 3) & ~(size_t)3;
    size_t need = (wf_off + 16 * (size_t)N + (size_t)NR * NB_BIN + 2 * (size_t)NR + 2 * (size_t)N + 2) * 4;
    if (ws_size >= need && NR <= MAX_NR && N <= (1 << 26)) {
        unsigned* binned   = (unsigned*)d_ws;
        unsigned* csr      = binned + E;
        unsigned* wf       = (unsigned*)d_ws + wf_off;
        unsigned* A        = wf + 16 * (size_t)N;
        unsigned* keytot   = A + (size_t)NR * NB_BIN;
        unsigned* rs       = keytot + NR;
        unsigned* rowstart = rs + NR + 1;
        float*    inv      = (float*)(rowstart + N + 1);

        binA_kernel<<<NB_BIN, 256, 0, stream>>>(edst, A, E, NR, chunk);
        scanA_kernel<<<(NR + SCANA_TR - 1) / SCANA_TR, 512, 0, stream>>>(A, keytot, NR);
        scanR_kernel<<<1, 1024, 0, stream>>>(keytot, rs, NR);
        binB_kernel<<<NB_BIN, 256, 0, stream>>>(esrc, edst, A, rs, binned, E, NR, chunk);
        build_kernel<<<NR, 256, 0, stream>>>(binned, rs, feat, wf, csr, rowstart, inv, N, E);
        {
            int waves_per_block = 4;  // 256 threads
            int grid = (N + waves_per_block - 1) / waves_per_block;
            gather_kernel<<<grid, 256, 0, stream>>>(feat, wf, csr, rowstart, inv, out, N);
        }
    } else {
        float* deg = (float*)d_ws;
        float* inv = deg + N;
        hipMemsetAsync(deg, 0, (size_t)N * sizeof(float), stream);
        hipMemsetAsync(out, 0, (size_t)ND * sizeof(float), stream);
        {
            int grid = (E + 255) / 256; if (grid > 2048) grid = 2048;
            fb_deg_kernel<<<grid, 256, 0, stream>>>(edst, deg, E);
        }
        fb_inv_kernel<<<(N + 255) / 256, 256, 0, stream>>>(deg, inv, N);
        {
            long long total = (long long)E * D_FEAT;
            fb_scatter_kernel<<<(int)((total + 255) / 256), 256, 0, stream>>>(feat, esrc, edst, inv, out, E);
        }
        fb_finalize_kernel<<<(ND + 255) / 256, 256, 0, stream>>>(feat, inv, out, ND);
    }
}

// Round 8
// 91.062 us; speedup vs baseline: 3.8251x; 1.0403x over previous
//
#include <hip/hip_runtime.h>

#define D_FEAT 32
#define RSH 6              // 64 nodes per range
#define RS_NODES 64
#define MAX_NR 2048        // max ranges (N <= 131072)
#define NB_BIN 512         // binning blocks
#define SCANA_TR 16        // ranges per scanA block
#define GATHER_BLOCKS 2048 // persistent gather grid

// round-to-nearest-even bf16 pack of two floats
__device__ __forceinline__ unsigned bfpack(float lo, float hi) {
    unsigned ul = __float_as_uint(lo), uh = __float_as_uint(hi);
    ul = (ul + 0x7FFFu + ((ul >> 16) & 1u)) >> 16;
    uh = (uh + 0x7FFFu + ((uh >> 16) & 1u)) >> 16;
    return ul | (uh << 16);
}

// Pass A: per-block LDS histogram of edge chunk by range key (dst>>6). No global atomics.
__global__ void binA_kernel(const int* __restrict__ dst, unsigned* __restrict__ A,
                            int E, int NR, int chunk) {
    __shared__ unsigned cnt[MAX_NR];
    for (int i = threadIdx.x; i < NR; i += blockDim.x) cnt[i] = 0u;
    __syncthreads();
    int b = blockIdx.x;
    int lo = b * chunk;
    int hi = min(lo + chunk, E);
    if (lo < hi) {
        int nq = (hi - lo) >> 2;
        const int4* p = (const int4*)(dst + lo);
        for (int q = threadIdx.x; q < nq; q += blockDim.x) {
            int4 v = p[q];
            atomicAdd(&cnt[v.x >> RSH], 1u);
            atomicAdd(&cnt[v.y >> RSH], 1u);
            atomicAdd(&cnt[v.z >> RSH], 1u);
            atomicAdd(&cnt[v.w >> RSH], 1u);
        }
        for (int i = lo + (nq << 2) + threadIdx.x; i < hi; i += blockDim.x)
            atomicAdd(&cnt[dst[i] >> RSH], 1u);
    }
    __syncthreads();
    for (int i = threadIdx.x; i < NR; i += blockDim.x)
        A[(size_t)b * NR + i] = cnt[i];
}

// Scan 1 (tiled transpose): stage 512 x SCANA_TR tile through LDS, shfl-scan bins.
__global__ void scanA_kernel(unsigned* __restrict__ A, unsigned* __restrict__ keytot, int NR) {
    __shared__ unsigned lds[SCANA_TR * 514];
    int r0 = blockIdx.x * SCANA_TR;
    int tid = threadIdx.x;  // 512 threads
    for (int idx = tid; idx < NB_BIN * SCANA_TR; idx += 512) {
        int c = idx & (SCANA_TR - 1);
        int b = idx >> 4;
        int r = r0 + c;
        lds[c * 514 + b] = (r < NR) ? A[(size_t)b * NR + r] : 0u;
    }
    __syncthreads();
    int wid = tid >> 6;
    int lane = tid & 63;
    #pragma unroll
    for (int cc = 0; cc < 2; cc++) {
        int c = wid * 2 + cc;
        unsigned carry = 0u;
        #pragma unroll
        for (int chunk = 0; chunk < NB_BIN / 64; chunk++) {
            unsigned v = lds[c * 514 + chunk * 64 + lane];
            unsigned incl = v;
            #pragma unroll
            for (int off = 1; off < 64; off <<= 1) {
                unsigned t = __shfl_up(incl, off, 64);
                if (lane >= off) incl += t;
            }
            lds[c * 514 + chunk * 64 + lane] = carry + incl - v;
            carry += __shfl(incl, 63, 64);
        }
        if (lane == 0 && (r0 + c) < NR) keytot[r0 + c] = carry;
    }
    __syncthreads();
    for (int idx = tid; idx < NB_BIN * SCANA_TR; idx += 512) {
        int c = idx & (SCANA_TR - 1);
        int b = idx >> 4;
        int r = r0 + c;
        if (r < NR) A[(size_t)b * NR + r] = lds[c * 514 + b];
    }
}

// Scan 2: exclusive scan of per-range totals -> rs[NR+1]. NR <= 2048.
__global__ void scanR_kernel(const unsigned* __restrict__ keytot, unsigned* __restrict__ rs, int NR) {
    __shared__ unsigned a[2][2048];
    int t = threadIdx.x;
    a[0][t]        = (t < NR)        ? keytot[t]        : 0u;
    a[0][t + 1024] = (t + 1024 < NR) ? keytot[t + 1024] : 0u;
    int pin = 0;
    for (int off = 1; off < 2048; off <<= 1) {
        __syncthreads();
        int po = pin ^ 1;
        #pragma unroll
        for (int k = 0; k < 2; k++) {
            int idx = t + k * 1024;
            unsigned x = a[pin][idx];
            if (idx >= off) x += a[pin][idx - off];
            a[po][idx] = x;
        }
        pin ^= 1;
    }
    __syncthreads();
    #pragma unroll
    for (int k = 0; k < 2; k++) {
        int idx = t + k * 1024;
        if (idx < NR) rs[idx] = idx ? a[pin][idx - 1] : 0u;
    }
    if (t == 0) rs[NR] = a[pin][2047];
}

// Pass B: place packed edge (src | (dst&63)<<26) into range-grouped order via LDS cursors.
__global__ void binB_kernel(const int* __restrict__ src, const int* __restrict__ dst,
                            const unsigned* __restrict__ A, const unsigned* __restrict__ rs,
                            unsigned* __restrict__ binned, int E, int NR, int chunk) {
    __shared__ unsigned cur[MAX_NR];
    int b = blockIdx.x;
    for (int i = threadIdx.x; i < NR; i += blockDim.x)
        cur[i] = rs[i] + A[(size_t)b * NR + i];
    __syncthreads();
    int lo = b * chunk;
    int hi = min(lo + chunk, E);
    if (lo >= hi) return;
    int nq = (hi - lo) >> 2;
    const int4* ps = (const int4*)(src + lo);
    const int4* pd = (const int4*)(dst + lo);
    for (int q = threadIdx.x; q < nq; q += blockDim.x) {
        int4 s = ps[q];
        int4 d = pd[q];
        unsigned p0 = atomicAdd(&cur[d.x >> RSH], 1u);
        binned[p0] = (unsigned)s.x | ((unsigned)(d.x & (RS_NODES - 1)) << 26);
        unsigned p1 = atomicAdd(&cur[d.y >> RSH], 1u);
        binned[p1] = (unsigned)s.y | ((unsigned)(d.y & (RS_NODES - 1)) << 26);
        unsigned p2 = atomicAdd(&cur[d.z >> RSH], 1u);
        binned[p2] = (unsigned)s.z | ((unsigned)(d.z & (RS_NODES - 1)) << 26);
        unsigned p3 = atomicAdd(&cur[d.w >> RSH], 1u);
        binned[p3] = (unsigned)s.w | ((unsigned)(d.w & (RS_NODES - 1)) << 26);
    }
    for (int i = lo + (nq << 2) + threadIdx.x; i < hi; i += blockDim.x) {
        unsigned p = atomicAdd(&cur[dst[i] >> RSH], 1u);
        binned[p] = (unsigned)src[i] | ((unsigned)(dst[i] & (RS_NODES - 1)) << 26);
    }
}

// Build per-node CSR within each range (count -> wave scan -> place) AND convert the
// range's 64 feature rows to pre-scaled bf16: wf[n] = bf16(inv[n]*feat[n]), 64 B/row.
__global__ void build_kernel(const unsigned* __restrict__ binned, const unsigned* __restrict__ rs,
                             const float* __restrict__ feat, unsigned* __restrict__ wf,
                             unsigned* __restrict__ csr, unsigned* __restrict__ rowstart,
                             float* __restrict__ inv, int N, int E) {
    __shared__ unsigned deg64[RS_NODES];
    __shared__ unsigned cur64[RS_NODES];
    __shared__ float sinv[RS_NODES];
    int r = blockIdx.x;
    if (threadIdx.x < RS_NODES) deg64[threadIdx.x] = 0u;
    __syncthreads();
    unsigned e0 = rs[r], e1 = rs[r + 1];
    for (unsigned e = e0 + threadIdx.x; e < e1; e += blockDim.x)
        atomicAdd(&deg64[binned[e] >> 26], 1u);
    __syncthreads();
    if (threadIdx.x < RS_NODES) {
        unsigned d = deg64[threadIdx.x];
        unsigned incl = d;
        #pragma unroll
        for (int off = 1; off < RS_NODES; off <<= 1) {
            unsigned t = __shfl_up(incl, off, 64);
            if (threadIdx.x >= (unsigned)off) incl += t;
        }
        unsigned startpos = e0 + (incl - d);
        cur64[threadIdx.x] = startpos;
        float ivv = rsqrtf(1.0f + (float)d);
        sinv[threadIdx.x] = ivv;
        int node = r * RS_NODES + threadIdx.x;
        if (node < N) {
            rowstart[node] = startpos;
            inv[node] = ivv;
        }
    }
    if (r == 0 && threadIdx.x == 0) rowstart[N] = (unsigned)E;
    __syncthreads();
    for (unsigned e = e0 + threadIdx.x; e < e1; e += blockDim.x) {
        unsigned p = binned[e];
        unsigned pos = atomicAdd(&cur64[p >> 26], 1u);
        csr[pos] = p & 0x03FFFFFFu;
    }
    {
        int nl = threadIdx.x >> 2;
        int q = threadIdx.x & 3;
        int node = r * RS_NODES + nl;
        if (node < N) {
            float ivv = sinv[nl];
            const float4* fp = (const float4*)(feat + (size_t)node * D_FEAT + q * 8);
            float4 a = fp[0];
            float4 b = fp[1];
            uint4 o;
            o.x = bfpack(ivv * a.x, ivv * a.y);
            o.y = bfpack(ivv * a.z, ivv * a.w);
            o.z = bfpack(ivv * b.x, ivv * b.y);
            o.w = bfpack(ivv * b.z, ivv * b.w);
            ((uint4*)wf)[(size_t)node * 4 + q] = o;
        }
    }
}

// PERSISTENT gather: 2048 blocks x 4 waves; each wave owns a contiguous chunk of nodes
// and loops. 8 groups x 8 lanes; lane q covers dims [4q,4q+4) via one uint2 (4 bf16)
// per edge -> one 64B line per edge row. fp32 accumulate; 12-shfl reduce.
__global__ void gather_kernel(const float* __restrict__ feat, const unsigned* __restrict__ wf,
                              const unsigned* __restrict__ csr, const unsigned* __restrict__ rowstart,
                              const float* __restrict__ inv, float* __restrict__ out,
                              int N, int per) {
    int w = blockIdx.x * (blockDim.x >> 6) + (threadIdx.x >> 6);
    int lane = threadIdx.x & 63;
    int g = lane >> 3;   // edge slot within iteration
    int q = lane & 7;    // dim quad: [4q, 4q+4)
    int n0 = w * per;
    int n1 = min(N, n0 + per);
    for (int node = n0; node < n1; ++node) {
        unsigned start = rowstart[node], end = rowstart[node + 1];
        float iv = inv[node];
        float4 acc = make_float4(0.f, 0.f, 0.f, 0.f);
        if (g == 0) {  // self-loop in fp32 (scaled by iv again at store)
            float4 f = *(const float4*)(feat + (size_t)node * D_FEAT + q * 4);
            acc.x = iv * f.x; acc.y = iv * f.y; acc.z = iv * f.z; acc.w = iv * f.w;
        }
        unsigned k = start + g;
        for (; k + 8 < end; k += 16) {
            unsigned j0 = csr[k], j1 = csr[k + 8];
            uint2 w0 = *(const uint2*)(wf + (size_t)j0 * 16 + q * 2);
            uint2 w1 = *(const uint2*)(wf + (size_t)j1 * 16 + q * 2);
            acc.x += __uint_as_float(w0.x << 16);
            acc.y += __uint_as_float(w0.x & 0xFFFF0000u);
            acc.z += __uint_as_float(w0.y << 16);
            acc.w += __uint_as_float(w0.y & 0xFFFF0000u);
            acc.x += __uint_as_float(w1.x << 16);
            acc.y += __uint_as_float(w1.x & 0xFFFF0000u);
            acc.z += __uint_as_float(w1.y << 16);
            acc.w += __uint_as_float(w1.y & 0xFFFF0000u);
        }
        if (k < end) {
            unsigned j = csr[k];
            uint2 wv = *(const uint2*)(wf + (size_t)j * 16 + q * 2);
            acc.x += __uint_as_float(wv.x << 16);
            acc.y += __uint_as_float(wv.x & 0xFFFF0000u);
            acc.z += __uint_as_float(wv.y << 16);
            acc.w += __uint_as_float(wv.y & 0xFFFF0000u);
        }
        #pragma unroll
        for (int off = 8; off < 64; off <<= 1) {
            acc.x += __shfl_xor(acc.x, off);
            acc.y += __shfl_xor(acc.y, off);
            acc.z += __shfl_xor(acc.z, off);
            acc.w += __shfl_xor(acc.w, off);
        }
        if (g == 0) {
            float4 rv;
            rv.x = iv * acc.x; rv.y = iv * acc.y; rv.z = iv * acc.z; rv.w = iv * acc.w;
            *(float4*)(out + (size_t)node * D_FEAT + q * 4) = rv;
        }
    }
}

// ---------- fallback (atomic scatter) if workspace too small ----------

__global__ void fb_deg_kernel(const int* __restrict__ dst, float* __restrict__ deg, int E) {
    int i = blockIdx.x * blockDim.x + threadIdx.x;
    int stride = gridDim.x * blockDim.x;
    for (; i < E; i += stride) atomicAdd(&deg[dst[i]], 1.0f);
}
__global__ void fb_inv_kernel(const float* __restrict__ deg, float* __restrict__ inv, int N) {
    int i = blockIdx.x * blockDim.x + threadIdx.x;
    if (i < N) inv[i] = rsqrtf(1.0f + deg[i]);
}
__global__ void fb_scatter_kernel(const float* __restrict__ feat, const int* __restrict__ src,
                                  const int* __restrict__ dst, const float* __restrict__ inv,
                                  float* __restrict__ out, int E) {
    long long tid = (long long)blockIdx.x * blockDim.x + threadIdx.x;
    int e = (int)(tid >> 5);
    int d = (int)(tid & 31);
    if (e >= E) return;
    int s = src[e];
    int t = dst[e];
    atomicAdd(&out[t * D_FEAT + d], inv[s] * feat[s * D_FEAT + d]);
}
__global__ void fb_finalize_kernel(const float* __restrict__ feat, const float* __restrict__ inv,
                                   float* __restrict__ out, int ND) {
    int tid = blockIdx.x * blockDim.x + threadIdx.x;
    if (tid >= ND) return;
    float iv = inv[tid >> 5];
    out[tid] = iv * (out[tid] + iv * feat[tid]);
}

extern "C" void kernel_launch(void* const* d_in, const int* in_sizes, int n_in,
                              void* d_out, int out_size, void* d_ws, size_t ws_size,
                              hipStream_t stream) {
    const float* feat = (const float*)d_in[0];
    const int* esrc = (const int*)d_in[1];
    const int* edst = (const int*)d_in[2];
    float* out = (float*)d_out;

    const int N = in_sizes[0] / D_FEAT;
    const int E = in_sizes[1];
    const int ND = N * D_FEAT;
    const int NR = (N + RS_NODES - 1) >> RSH;
    const int chunk = (((E + NB_BIN - 1) / NB_BIN) + 3) & ~3;

    size_t wf_off = ((size_t)2 * E + 3) & ~(size_t)3;
    size_t need = (wf_off + 16 * (size_t)N + (size_t)NR * NB_BIN + 2 * (size_t)NR + 2 * (size_t)N + 2) * 4;
    if (ws_size >= need && NR <= MAX_NR && N <= (1 << 26)) {
        unsigned* binned   = (unsigned*)d_ws;
        unsigned* csr      = binned + E;
        unsigned* wf       = (unsigned*)d_ws + wf_off;
        unsigned* A        = wf + 16 * (size_t)N;
        unsigned* keytot   = A + (size_t)NR * NB_BIN;
        unsigned* rs       = keytot + NR;
        unsigned* rowstart = rs + NR + 1;
        float*    inv      = (float*)(rowstart + N + 1);

        binA_kernel<<<NB_BIN, 256, 0, stream>>>(edst, A, E, NR, chunk);
        scanA_kernel<<<(NR + SCANA_TR - 1) / SCANA_TR, 512, 0, stream>>>(A, keytot, NR);
        scanR_kernel<<<1, 1024, 0, stream>>>(keytot, rs, NR);
        binB_kernel<<<NB_BIN, 256, 0, stream>>>(esrc, edst, A, rs, binned, E, NR, chunk);
        build_kernel<<<NR, 256, 0, stream>>>(binned, rs, feat, wf, csr, rowstart, inv, N, E);
        {
            int total_waves = GATHER_BLOCKS * 4;
            int per = (N + total_waves - 1) / total_waves;
            gather_kernel<<<GATHER_BLOCKS, 256, 0, stream>>>(feat, wf, csr, rowstart, inv, out, N, per);
        }
    } else {
        float* deg = (float*)d_ws;
        float* inv = deg + N;
        hipMemsetAsync(deg, 0, (size_t)N * sizeof(float), stream);
        hipMemsetAsync(out, 0, (size_t)ND * sizeof(float), stream);
        {
            int grid = (E + 255) / 256; if (grid > 2048) grid = 2048;
            fb_deg_kernel<<<grid, 256, 0, stream>>>(edst, deg, E);
        }
        fb_inv_kernel<<<(N + 255) / 256, 256, 0, stream>>>(deg, inv, N);
        {
            long long total = (long long)E * D_FEAT;
            fb_scatter_kernel<<<(int)((total + 255) / 256), 256, 0, stream>>>(feat, esrc, edst, inv, out, E);
        }
        fb_finalize_kernel<<<(ND + 255) / 256, 256, 0, stream>>>(feat, inv, out, ND);
    }
}

// Round 9
// 84.895 us; speedup vs baseline: 4.1030x; 1.0726x over previous
//
#include <hip/hip_runtime.h>

#define D_FEAT 32
#define RSH 8              // 256 nodes per range
#define RS_NODES 256
#define LOCAL_SHIFT 24     // pack: src | (dst&255)<<24  (needs N <= 2^24)
#define SRC_MASK 0x00FFFFFFu
#define MAX_NR 2048
#define NB_BIN 512         // binning blocks
#define SCANA_TR 16        // ranges per scanA block
#define GATHER_BLOCKS 2048 // persistent gather grid

// round-to-nearest-even bf16 pack of two floats
__device__ __forceinline__ unsigned bfpack(float lo, float hi) {
    unsigned ul = __float_as_uint(lo), uh = __float_as_uint(hi);
    ul = (ul + 0x7FFFu + ((ul >> 16) & 1u)) >> 16;
    uh = (uh + 0x7FFFu + ((uh >> 16) & 1u)) >> 16;
    return ul | (uh << 16);
}

// Pass A: per-block LDS histogram of edge chunk by range key (dst>>8). No global atomics.
__global__ void binA_kernel(const int* __restrict__ dst, unsigned* __restrict__ A,
                            int E, int NR, int chunk) {
    __shared__ unsigned cnt[MAX_NR];
    for (int i = threadIdx.x; i < NR; i += blockDim.x) cnt[i] = 0u;
    __syncthreads();
    int b = blockIdx.x;
    int lo = b * chunk;
    int hi = min(lo + chunk, E);
    if (lo < hi) {
        int nq = (hi - lo) >> 2;
        const int4* p = (const int4*)(dst + lo);
        for (int q = threadIdx.x; q < nq; q += blockDim.x) {
            int4 v = p[q];
            atomicAdd(&cnt[v.x >> RSH], 1u);
            atomicAdd(&cnt[v.y >> RSH], 1u);
            atomicAdd(&cnt[v.z >> RSH], 1u);
            atomicAdd(&cnt[v.w >> RSH], 1u);
        }
        for (int i = lo + (nq << 2) + threadIdx.x; i < hi; i += blockDim.x)
            atomicAdd(&cnt[dst[i] >> RSH], 1u);
    }
    __syncthreads();
    for (int i = threadIdx.x; i < NR; i += blockDim.x)
        A[(size_t)b * NR + i] = cnt[i];
}

// Scan 1 (tiled transpose): stage 512 x SCANA_TR tile through LDS, shfl-scan bins.
__global__ void scanA_kernel(unsigned* __restrict__ A, unsigned* __restrict__ keytot, int NR) {
    __shared__ unsigned lds[SCANA_TR * 514];
    int r0 = blockIdx.x * SCANA_TR;
    int tid = threadIdx.x;  // 512 threads
    for (int idx = tid; idx < NB_BIN * SCANA_TR; idx += 512) {
        int c = idx & (SCANA_TR - 1);
        int b = idx >> 4;
        int r = r0 + c;
        lds[c * 514 + b] = (r < NR) ? A[(size_t)b * NR + r] : 0u;
    }
    __syncthreads();
    int wid = tid >> 6;
    int lane = tid & 63;
    #pragma unroll
    for (int cc = 0; cc < 2; cc++) {
        int c = wid * 2 + cc;
        unsigned carry = 0u;
        #pragma unroll
        for (int chunk = 0; chunk < NB_BIN / 64; chunk++) {
            unsigned v = lds[c * 514 + chunk * 64 + lane];
            unsigned incl = v;
            #pragma unroll
            for (int off = 1; off < 64; off <<= 1) {
                unsigned t = __shfl_up(incl, off, 64);
                if (lane >= off) incl += t;
            }
            lds[c * 514 + chunk * 64 + lane] = carry + incl - v;
            carry += __shfl(incl, 63, 64);
        }
        if (lane == 0 && (r0 + c) < NR) keytot[r0 + c] = carry;
    }
    __syncthreads();
    for (int idx = tid; idx < NB_BIN * SCANA_TR; idx += 512) {
        int c = idx & (SCANA_TR - 1);
        int b = idx >> 4;
        int r = r0 + c;
        if (r < NR) A[(size_t)b * NR + r] = lds[c * 514 + b];
    }
}

// Scan 2: exclusive scan of per-range totals -> rs[NR+1]. NR <= 2048.
__global__ void scanR_kernel(const unsigned* __restrict__ keytot, unsigned* __restrict__ rs, int NR) {
    __shared__ unsigned a[2][2048];
    int t = threadIdx.x;
    a[0][t]        = (t < NR)        ? keytot[t]        : 0u;
    a[0][t + 1024] = (t + 1024 < NR) ? keytot[t + 1024] : 0u;
    int pin = 0;
    for (int off = 1; off < 2048; off <<= 1) {
        __syncthreads();
        int po = pin ^ 1;
        #pragma unroll
        for (int k = 0; k < 2; k++) {
            int idx = t + k * 1024;
            unsigned x = a[pin][idx];
            if (idx >= off) x += a[pin][idx - off];
            a[po][idx] = x;
        }
        pin ^= 1;
    }
    __syncthreads();
    #pragma unroll
    for (int k = 0; k < 2; k++) {
        int idx = t + k * 1024;
        if (idx < NR) rs[idx] = idx ? a[pin][idx - 1] : 0u;
    }
    if (t == 0) rs[NR] = a[pin][2047];
}

// Pass B: place packed edge (src | (dst&255)<<24) into range-grouped order via LDS cursors.
__global__ void binB_kernel(const int* __restrict__ src, const int* __restrict__ dst,
                            const unsigned* __restrict__ A, const unsigned* __restrict__ rs,
                            unsigned* __restrict__ binned, int E, int NR, int chunk) {
    __shared__ unsigned cur[MAX_NR];
    int b = blockIdx.x;
    for (int i = threadIdx.x; i < NR; i += blockDim.x)
        cur[i] = rs[i] + A[(size_t)b * NR + i];
    __syncthreads();
    int lo = b * chunk;
    int hi = min(lo + chunk, E);
    if (lo >= hi) return;
    int nq = (hi - lo) >> 2;
    const int4* ps = (const int4*)(src + lo);
    const int4* pd = (const int4*)(dst + lo);
    for (int q = threadIdx.x; q < nq; q += blockDim.x) {
        int4 s = ps[q];
        int4 d = pd[q];
        unsigned p0 = atomicAdd(&cur[d.x >> RSH], 1u);
        binned[p0] = (unsigned)s.x | ((unsigned)(d.x & (RS_NODES - 1)) << LOCAL_SHIFT);
        unsigned p1 = atomicAdd(&cur[d.y >> RSH], 1u);
        binned[p1] = (unsigned)s.y | ((unsigned)(d.y & (RS_NODES - 1)) << LOCAL_SHIFT);
        unsigned p2 = atomicAdd(&cur[d.z >> RSH], 1u);
        binned[p2] = (unsigned)s.z | ((unsigned)(d.z & (RS_NODES - 1)) << LOCAL_SHIFT);
        unsigned p3 = atomicAdd(&cur[d.w >> RSH], 1u);
        binned[p3] = (unsigned)s.w | ((unsigned)(d.w & (RS_NODES - 1)) << LOCAL_SHIFT);
    }
    for (int i = lo + (nq << 2) + threadIdx.x; i < hi; i += blockDim.x) {
        unsigned p = atomicAdd(&cur[dst[i] >> RSH], 1u);
        binned[p] = (unsigned)src[i] | ((unsigned)(dst[i] & (RS_NODES - 1)) << LOCAL_SHIFT);
    }
}

// Build per-node CSR within each 256-node range (count -> 256-wide block scan -> place)
// AND convert the range's rows to pre-scaled bf16: wf[n] = bf16(inv[n]*feat[n]).
__global__ void build_kernel(const unsigned* __restrict__ binned, const unsigned* __restrict__ rs,
                             const float* __restrict__ feat, unsigned* __restrict__ wf,
                             unsigned* __restrict__ csr, unsigned* __restrict__ rowstart,
                             float* __restrict__ inv, int N, int E) {
    __shared__ unsigned deg_l[RS_NODES];
    __shared__ unsigned cur_l[RS_NODES];
    __shared__ float sinv[RS_NODES];
    __shared__ unsigned wtot[4];
    int r = blockIdx.x;
    int tid = threadIdx.x;  // 256
    deg_l[tid] = 0u;
    __syncthreads();
    unsigned e0 = rs[r], e1 = rs[r + 1];
    for (unsigned e = e0 + tid; e < e1; e += RS_NODES)
        atomicAdd(&deg_l[binned[e] >> LOCAL_SHIFT], 1u);
    __syncthreads();
    unsigned d = deg_l[tid];
    int lane = tid & 63, w = tid >> 6;
    unsigned incl = d;
    #pragma unroll
    for (int off = 1; off < 64; off <<= 1) {
        unsigned t = __shfl_up(incl, off, 64);
        if (lane >= off) incl += t;
    }
    if (lane == 63) wtot[w] = incl;
    __syncthreads();
    unsigned woff = 0;
    #pragma unroll
    for (int i = 0; i < 4; i++) if (i < w) woff += wtot[i];
    unsigned base = e0 + woff + incl - d;   // exclusive position for node tid
    cur_l[tid] = base;
    float ivv = rsqrtf(1.0f + (float)d);
    sinv[tid] = ivv;
    int node = r * RS_NODES + tid;
    if (node < N) {
        rowstart[node] = base;
        inv[node] = ivv;
    }
    if (r == 0 && tid == 0) rowstart[N] = (unsigned)E;
    __syncthreads();
    for (unsigned e = e0 + tid; e < e1; e += RS_NODES) {
        unsigned p = binned[e];
        unsigned pos = atomicAdd(&cur_l[p >> LOCAL_SHIFT], 1u);
        csr[pos] = p & SRC_MASK;
    }
    // wf conversion: 256 nodes x 4 quads (each quad = 8 dims -> one uint4)
    for (int i = tid; i < RS_NODES * 4; i += RS_NODES) {
        int nl = i >> 2, q = i & 3;
        int nn = r * RS_NODES + nl;
        if (nn < N) {
            float iw = sinv[nl];
            const float4* fp = (const float4*)(feat + (size_t)nn * D_FEAT + q * 8);
            float4 a = fp[0], b = fp[1];
            uint4 o;
            o.x = bfpack(iw * a.x, iw * a.y);
            o.y = bfpack(iw * a.z, iw * a.w);
            o.z = bfpack(iw * b.x, iw * b.y);
            o.w = bfpack(iw * b.z, iw * b.w);
            ((uint4*)wf)[(size_t)nn * 4 + q] = o;
        }
    }
}

// PERSISTENT gather: 2048 blocks x 4 waves; each wave owns a contiguous node chunk.
// 8 groups x 8 lanes; lane q covers dims [4q,4q+4) via one uint2 (4 bf16) per edge.
__global__ void gather_kernel(const float* __restrict__ feat, const unsigned* __restrict__ wf,
                              const unsigned* __restrict__ csr, const unsigned* __restrict__ rowstart,
                              const float* __restrict__ inv, float* __restrict__ out,
                              int N, int per) {
    int w = blockIdx.x * (blockDim.x >> 6) + (threadIdx.x >> 6);
    int lane = threadIdx.x & 63;
    int g = lane >> 3;
    int q = lane & 7;
    int n0 = w * per;
    int n1 = min(N, n0 + per);
    for (int node = n0; node < n1; ++node) {
        unsigned start = rowstart[node], end = rowstart[node + 1];
        float iv = inv[node];
        float4 acc = make_float4(0.f, 0.f, 0.f, 0.f);
        if (g == 0) {  // self-loop in fp32 (scaled by iv again at store)
            float4 f = *(const float4*)(feat + (size_t)node * D_FEAT + q * 4);
            acc.x = iv * f.x; acc.y = iv * f.y; acc.z = iv * f.z; acc.w = iv * f.w;
        }
        unsigned k = start + g;
        for (; k + 8 < end; k += 16) {
            unsigned j0 = csr[k], j1 = csr[k + 8];
            uint2 w0 = *(const uint2*)(wf + (size_t)j0 * 16 + q * 2);
            uint2 w1 = *(const uint2*)(wf + (size_t)j1 * 16 + q * 2);
            acc.x += __uint_as_float(w0.x << 16);
            acc.y += __uint_as_float(w0.x & 0xFFFF0000u);
            acc.z += __uint_as_float(w0.y << 16);
            acc.w += __uint_as_float(w0.y & 0xFFFF0000u);
            acc.x += __uint_as_float(w1.x << 16);
            acc.y += __uint_as_float(w1.x & 0xFFFF0000u);
            acc.z += __uint_as_float(w1.y << 16);
            acc.w += __uint_as_float(w1.y & 0xFFFF0000u);
        }
        if (k < end) {
            unsigned j = csr[k];
            uint2 wv = *(const uint2*)(wf + (size_t)j * 16 + q * 2);
            acc.x += __uint_as_float(wv.x << 16);
            acc.y += __uint_as_float(wv.x & 0xFFFF0000u);
            acc.z += __uint_as_float(wv.y << 16);
            acc.w += __uint_as_float(wv.y & 0xFFFF0000u);
        }
        #pragma unroll
        for (int off = 8; off < 64; off <<= 1) {
            acc.x += __shfl_xor(acc.x, off);
            acc.y += __shfl_xor(acc.y, off);
            acc.z += __shfl_xor(acc.z, off);
            acc.w += __shfl_xor(acc.w, off);
        }
        if (g == 0) {
            float4 rv;
            rv.x = iv * acc.x; rv.y = iv * acc.y; rv.z = iv * acc.z; rv.w = iv * acc.w;
            *(float4*)(out + (size_t)node * D_FEAT + q * 4) = rv;
        }
    }
}

// ---------- fallback (atomic scatter) if workspace too small ----------

__global__ void fb_deg_kernel(const int* __restrict__ dst, float* __restrict__ deg, int E) {
    int i = blockIdx.x * blockDim.x + threadIdx.x;
    int stride = gridDim.x * blockDim.x;
    for (; i < E; i += stride) atomicAdd(&deg[dst[i]], 1.0f);
}
__global__ void fb_inv_kernel(const float* __restrict__ deg, float* __restrict__ inv, int N) {
    int i = blockIdx.x * blockDim.x + threadIdx.x;
    if (i < N) inv[i] = rsqrtf(1.0f + deg[i]);
}
__global__ void fb_scatter_kernel(const float* __restrict__ feat, const int* __restrict__ src,
                                  const int* __restrict__ dst, const float* __restrict__ inv,
                                  float* __restrict__ out, int E) {
    long long tid = (long long)blockIdx.x * blockDim.x + threadIdx.x;
    int e = (int)(tid >> 5);
    int d = (int)(tid & 31);
    if (e >= E) return;
    int s = src[e];
    int t = dst[e];
    atomicAdd(&out[t * D_FEAT + d], inv[s] * feat[s * D_FEAT + d]);
}
__global__ void fb_finalize_kernel(const float* __restrict__ feat, const float* __restrict__ inv,
                                   float* __restrict__ out, int ND) {
    int tid = blockIdx.x * blockDim.x + threadIdx.x;
    if (tid >= ND) return;
    float iv = inv[tid >> 5];
    out[tid] = iv * (out[tid] + iv * feat[tid]);
}

extern "C" void kernel_launch(void* const* d_in, const int* in_sizes, int n_in,
                              void* d_out, int out_size, void* d_ws, size_t ws_size,
                              hipStream_t stream) {
    const float* feat = (const float*)d_in[0];
    const int* esrc = (const int*)d_in[1];
    const int* edst = (const int*)d_in[2];
    float* out = (float*)d_out;

    const int N = in_sizes[0] / D_FEAT;
    const int E = in_sizes[1];
    const int ND = N * D_FEAT;
    const int NR = (N + RS_NODES - 1) >> RSH;
    const int chunk = (((E + NB_BIN - 1) / NB_BIN) + 3) & ~3;

    size_t wf_off = ((size_t)2 * E + 3) & ~(size_t)3;
    size_t need = (wf_off + 16 * (size_t)N + (size_t)NR * NB_BIN + 2 * (size_t)NR + 2 * (size_t)N + 2) * 4;
    if (ws_size >= need && NR <= MAX_NR && N <= (1 << LOCAL_SHIFT)) {
        unsigned* binned   = (unsigned*)d_ws;
        unsigned* csr      = binned + E;
        unsigned* wf       = (unsigned*)d_ws + wf_off;
        unsigned* A        = wf + 16 * (size_t)N;
        unsigned* keytot   = A + (size_t)NR * NB_BIN;
        unsigned* rs       = keytot + NR;
        unsigned* rowstart = rs + NR + 1;
        float*    inv      = (float*)(rowstart + N + 1);

        binA_kernel<<<NB_BIN, 256, 0, stream>>>(edst, A, E, NR, chunk);
        scanA_kernel<<<(NR + SCANA_TR - 1) / SCANA_TR, 512, 0, stream>>>(A, keytot, NR);
        scanR_kernel<<<1, 1024, 0, stream>>>(keytot, rs, NR);
        binB_kernel<<<NB_BIN, 256, 0, stream>>>(esrc, edst, A, rs, binned, E, NR, chunk);
        build_kernel<<<NR, RS_NODES, 0, stream>>>(binned, rs, feat, wf, csr, rowstart, inv, N, E);
        {
            int total_waves = GATHER_BLOCKS * 4;
            int per = (N + total_waves - 1) / total_waves;
            gather_kernel<<<GATHER_BLOCKS, 256, 0, stream>>>(feat, wf, csr, rowstart, inv, out, N, per);
        }
    } else {
        float* deg = (float*)d_ws;
        float* inv = deg + N;
        hipMemsetAsync(deg, 0, (size_t)N * sizeof(float), stream);
        hipMemsetAsync(out, 0, (size_t)ND * sizeof(float), stream);
        {
            int grid = (E + 255) / 256; if (grid > 2048) grid = 2048;
            fb_deg_kernel<<<grid, 256, 0, stream>>>(edst, deg, E);
        }
        fb_inv_kernel<<<(N + 255) / 256, 256, 0, stream>>>(deg, inv, N);
        {
            long long total = (long long)E * D_FEAT;
            fb_scatter_kernel<<<(int)((total + 255) / 256), 256, 0, stream>>>(feat, esrc, edst, inv, out, E);
        }
        fb_finalize_kernel<<<(ND + 255) / 256, 256, 0, stream>>>(feat, inv, out, ND);
    }
}

// Round 10
// 83.568 us; speedup vs baseline: 4.1681x; 1.0159x over previous
//
#include <hip/hip_runtime.h>

#define D_FEAT 32
#define RSH 8              // 256 nodes per range
#define RS_NODES 256
#define LOCAL_SHIFT 24     // pack: src | (dst&255)<<24  (needs N <= 2^24)
#define SRC_MASK 0x00FFFFFFu
#define MAX_NR 2048
#define NB_BIN 512         // binning blocks
#define SCANA_TR 16        // ranges per scanA block
#define GATHER_BLOCKS 2048 // persistent gather grid

// round-to-nearest-even bf16 pack of two floats
__device__ __forceinline__ unsigned bfpack(float lo, float hi) {
    unsigned ul = __float_as_uint(lo), uh = __float_as_uint(hi);
    ul = (ul + 0x7FFFu + ((ul >> 16) & 1u)) >> 16;
    uh = (uh + 0x7FFFu + ((uh >> 16) & 1u)) >> 16;
    return ul | (uh << 16);
}

__device__ __forceinline__ void bfadd(float4& a, uint2 w) {
    a.x += __uint_as_float(w.x << 16);
    a.y += __uint_as_float(w.x & 0xFFFF0000u);
    a.z += __uint_as_float(w.y << 16);
    a.w += __uint_as_float(w.y & 0xFFFF0000u);
}

// Pass A: per-block LDS histogram of edge chunk by range key (dst>>8). No global atomics.
__global__ void binA_kernel(const int* __restrict__ dst, unsigned* __restrict__ A,
                            int E, int NR, int chunk) {
    __shared__ unsigned cnt[MAX_NR];
    for (int i = threadIdx.x; i < NR; i += blockDim.x) cnt[i] = 0u;
    __syncthreads();
    int b = blockIdx.x;
    int lo = b * chunk;
    int hi = min(lo + chunk, E);
    if (lo < hi) {
        int nq = (hi - lo) >> 2;
        const int4* p = (const int4*)(dst + lo);
        for (int q = threadIdx.x; q < nq; q += blockDim.x) {
            int4 v = p[q];
            atomicAdd(&cnt[v.x >> RSH], 1u);
            atomicAdd(&cnt[v.y >> RSH], 1u);
            atomicAdd(&cnt[v.z >> RSH], 1u);
            atomicAdd(&cnt[v.w >> RSH], 1u);
        }
        for (int i = lo + (nq << 2) + threadIdx.x; i < hi; i += blockDim.x)
            atomicAdd(&cnt[dst[i] >> RSH], 1u);
    }
    __syncthreads();
    for (int i = threadIdx.x; i < NR; i += blockDim.x)
        A[(size_t)b * NR + i] = cnt[i];
}

// Scan 1 (tiled transpose): stage 512 x SCANA_TR tile through LDS, shfl-scan bins.
__global__ void scanA_kernel(unsigned* __restrict__ A, unsigned* __restrict__ keytot, int NR) {
    __shared__ unsigned lds[SCANA_TR * 514];
    int r0 = blockIdx.x * SCANA_TR;
    int tid = threadIdx.x;  // 512 threads
    for (int idx = tid; idx < NB_BIN * SCANA_TR; idx += 512) {
        int c = idx & (SCANA_TR - 1);
        int b = idx >> 4;
        int r = r0 + c;
        lds[c * 514 + b] = (r < NR) ? A[(size_t)b * NR + r] : 0u;
    }
    __syncthreads();
    int wid = tid >> 6;
    int lane = tid & 63;
    #pragma unroll
    for (int cc = 0; cc < 2; cc++) {
        int c = wid * 2 + cc;
        unsigned carry = 0u;
        #pragma unroll
        for (int chunk = 0; chunk < NB_BIN / 64; chunk++) {
            unsigned v = lds[c * 514 + chunk * 64 + lane];
            unsigned incl = v;
            #pragma unroll
            for (int off = 1; off < 64; off <<= 1) {
                unsigned t = __shfl_up(incl, off, 64);
                if (lane >= off) incl += t;
            }
            lds[c * 514 + chunk * 64 + lane] = carry + incl - v;
            carry += __shfl(incl, 63, 64);
        }
        if (lane == 0 && (r0 + c) < NR) keytot[r0 + c] = carry;
    }
    __syncthreads();
    for (int idx = tid; idx < NB_BIN * SCANA_TR; idx += 512) {
        int c = idx & (SCANA_TR - 1);
        int b = idx >> 4;
        int r = r0 + c;
        if (r < NR) A[(size_t)b * NR + r] = lds[c * 514 + b];
    }
}

// Scan 2: exclusive scan of per-range totals -> rs[NR+1]. NR <= 2048.
__global__ void scanR_kernel(const unsigned* __restrict__ keytot, unsigned* __restrict__ rs, int NR) {
    __shared__ unsigned a[2][2048];
    int t = threadIdx.x;
    a[0][t]        = (t < NR)        ? keytot[t]        : 0u;
    a[0][t + 1024] = (t + 1024 < NR) ? keytot[t + 1024] : 0u;
    int pin = 0;
    for (int off = 1; off < 2048; off <<= 1) {
        __syncthreads();
        int po = pin ^ 1;
        #pragma unroll
        for (int k = 0; k < 2; k++) {
            int idx = t + k * 1024;
            unsigned x = a[pin][idx];
            if (idx >= off) x += a[pin][idx - off];
            a[po][idx] = x;
        }
        pin ^= 1;
    }
    __syncthreads();
    #pragma unroll
    for (int k = 0; k < 2; k++) {
        int idx = t + k * 1024;
        if (idx < NR) rs[idx] = idx ? a[pin][idx - 1] : 0u;
    }
    if (t == 0) rs[NR] = a[pin][2047];
}

// Pass B: place packed edge (src | (dst&255)<<24) into range-grouped order via LDS cursors.
__global__ void binB_kernel(const int* __restrict__ src, const int* __restrict__ dst,
                            const unsigned* __restrict__ A, const unsigned* __restrict__ rs,
                            unsigned* __restrict__ binned, int E, int NR, int chunk) {
    __shared__ unsigned cur[MAX_NR];
    int b = blockIdx.x;
    for (int i = threadIdx.x; i < NR; i += blockDim.x)
        cur[i] = rs[i] + A[(size_t)b * NR + i];
    __syncthreads();
    int lo = b * chunk;
    int hi = min(lo + chunk, E);
    if (lo >= hi) return;
    int nq = (hi - lo) >> 2;
    const int4* ps = (const int4*)(src + lo);
    const int4* pd = (const int4*)(dst + lo);
    for (int q = threadIdx.x; q < nq; q += blockDim.x) {
        int4 s = ps[q];
        int4 d = pd[q];
        unsigned p0 = atomicAdd(&cur[d.x >> RSH], 1u);
        binned[p0] = (unsigned)s.x | ((unsigned)(d.x & (RS_NODES - 1)) << LOCAL_SHIFT);
        unsigned p1 = atomicAdd(&cur[d.y >> RSH], 1u);
        binned[p1] = (unsigned)s.y | ((unsigned)(d.y & (RS_NODES - 1)) << LOCAL_SHIFT);
        unsigned p2 = atomicAdd(&cur[d.z >> RSH], 1u);
        binned[p2] = (unsigned)s.z | ((unsigned)(d.z & (RS_NODES - 1)) << LOCAL_SHIFT);
        unsigned p3 = atomicAdd(&cur[d.w >> RSH], 1u);
        binned[p3] = (unsigned)s.w | ((unsigned)(d.w & (RS_NODES - 1)) << LOCAL_SHIFT);
    }
    for (int i = lo + (nq << 2) + threadIdx.x; i < hi; i += blockDim.x) {
        unsigned p = atomicAdd(&cur[dst[i] >> RSH], 1u);
        binned[p] = (unsigned)src[i] | ((unsigned)(dst[i] & (RS_NODES - 1)) << LOCAL_SHIFT);
    }
}

// Build per-node CSR within each 256-node range (count -> 256-wide block scan -> place),
// emit nodeinfo ni[n] = {rowstart, inv-bits}, and convert rows to pre-scaled bf16 wf.
__global__ void build_kernel(const unsigned* __restrict__ binned, const unsigned* __restrict__ rs,
                             const float* __restrict__ feat, unsigned* __restrict__ wf,
                             unsigned* __restrict__ csr, uint2* __restrict__ ni,
                             int N, int E) {
    __shared__ unsigned deg_l[RS_NODES];
    __shared__ unsigned cur_l[RS_NODES];
    __shared__ float sinv[RS_NODES];
    __shared__ unsigned wtot[4];
    int r = blockIdx.x;
    int tid = threadIdx.x;  // 256
    deg_l[tid] = 0u;
    __syncthreads();
    unsigned e0 = rs[r], e1 = rs[r + 1];
    for (unsigned e = e0 + tid; e < e1; e += RS_NODES)
        atomicAdd(&deg_l[binned[e] >> LOCAL_SHIFT], 1u);
    __syncthreads();
    unsigned d = deg_l[tid];
    int lane = tid & 63, w = tid >> 6;
    unsigned incl = d;
    #pragma unroll
    for (int off = 1; off < 64; off <<= 1) {
        unsigned t = __shfl_up(incl, off, 64);
        if (lane >= off) incl += t;
    }
    if (lane == 63) wtot[w] = incl;
    __syncthreads();
    unsigned woff = 0;
    #pragma unroll
    for (int i = 0; i < 4; i++) if (i < w) woff += wtot[i];
    unsigned base = e0 + woff + incl - d;   // exclusive position for node tid
    cur_l[tid] = base;
    float ivv = rsqrtf(1.0f + (float)d);
    sinv[tid] = ivv;
    int node = r * RS_NODES + tid;
    if (node < N) ni[node] = make_uint2(base, __float_as_uint(ivv));
    if (r == 0 && tid == 0) ni[N] = make_uint2((unsigned)E, 0u);
    __syncthreads();
    for (unsigned e = e0 + tid; e < e1; e += RS_NODES) {
        unsigned p = binned[e];
        unsigned pos = atomicAdd(&cur_l[p >> LOCAL_SHIFT], 1u);
        csr[pos] = p & SRC_MASK;
    }
    // wf conversion: 256 nodes x 4 quads (each quad = 8 dims -> one uint4)
    for (int i = tid; i < RS_NODES * 4; i += RS_NODES) {
        int nl = i >> 2, q = i & 3;
        int nn = r * RS_NODES + nl;
        if (nn < N) {
            float iw = sinv[nl];
            const float4* fp = (const float4*)(feat + (size_t)nn * D_FEAT + q * 8);
            float4 a = fp[0], b = fp[1];
            uint4 o;
            o.x = bfpack(iw * a.x, iw * a.y);
            o.y = bfpack(iw * a.z, iw * a.w);
            o.z = bfpack(iw * b.x, iw * b.y);
            o.w = bfpack(iw * b.z, iw * b.w);
            ((uint4*)wf)[(size_t)nn * 4 + q] = o;
        }
    }
}

// PERSISTENT gather v2: straight-line predicated 16-slot body (pipelineable), self-loop
// from wf (no fp32 feat reads), nodeinfo uint2 carried across the node loop.
// 8 groups x 8 lanes; lane q covers dims [4q,4q+4) via one uint2 (4 bf16) per edge.
__global__ void gather_kernel(const unsigned* __restrict__ wf, const unsigned* __restrict__ csr,
                              const uint2* __restrict__ ni, float* __restrict__ out,
                              int N, int per) {
    int w = blockIdx.x * (blockDim.x >> 6) + (threadIdx.x >> 6);
    int lane = threadIdx.x & 63;
    int g = lane >> 3;
    int q = lane & 7;
    int n0 = w * per;
    int n1 = min(N, n0 + per);
    if (n0 >= n1) return;
    uint2 cur = ni[n0];
    for (int node = n0; node < n1; ++node) {
        uint2 nxt = ni[node + 1];
        unsigned start = cur.x, end = nxt.x;
        float iv = __uint_as_float(cur.y);
        float4 acc = make_float4(0.f, 0.f, 0.f, 0.f);
        // self-loop from wf (bf16 pre-scaled row)
        uint2 ws = *(const uint2*)(wf + (size_t)node * 16 + q * 2);
        if (g == 0) bfadd(acc, ws);
        // straight-line 16 predicated edge slots (2 per group)
        unsigned k0 = start + g, k1 = start + 8 + g;
        unsigned j0 = (k0 < end) ? csr[k0] : (unsigned)node;
        unsigned j1 = (k1 < end) ? csr[k1] : (unsigned)node;
        uint2 w0 = *(const uint2*)(wf + (size_t)j0 * 16 + q * 2);
        uint2 w1 = *(const uint2*)(wf + (size_t)j1 * 16 + q * 2);
        if (k0 < end) bfadd(acc, w0);
        if (k1 < end) bfadd(acc, w1);
        // rare tail for deg > 16
        unsigned k = start + 16 + g;
        if (k < end) {
            for (; k + 8 < end; k += 16) {
                unsigned ja = csr[k], jb = csr[k + 8];
                uint2 wa = *(const uint2*)(wf + (size_t)ja * 16 + q * 2);
                uint2 wb = *(const uint2*)(wf + (size_t)jb * 16 + q * 2);
                bfadd(acc, wa);
                bfadd(acc, wb);
            }
            if (k < end) {
                unsigned jc = csr[k];
                uint2 wc = *(const uint2*)(wf + (size_t)jc * 16 + q * 2);
                bfadd(acc, wc);
            }
        }
        #pragma unroll
        for (int off = 8; off < 64; off <<= 1) {
            acc.x += __shfl_xor(acc.x, off);
            acc.y += __shfl_xor(acc.y, off);
            acc.z += __shfl_xor(acc.z, off);
            acc.w += __shfl_xor(acc.w, off);
        }
        if (g == 0) {
            float4 rv;
            rv.x = iv * acc.x; rv.y = iv * acc.y; rv.z = iv * acc.z; rv.w = iv * acc.w;
            *(float4*)(out + (size_t)node * D_FEAT + q * 4) = rv;
        }
        cur = nxt;
    }
}

// ---------- fallback (atomic scatter) if workspace too small ----------

__global__ void fb_deg_kernel(const int* __restrict__ dst, float* __restrict__ deg, int E) {
    int i = blockIdx.x * blockDim.x + threadIdx.x;
    int stride = gridDim.x * blockDim.x;
    for (; i < E; i += stride) atomicAdd(&deg[dst[i]], 1.0f);
}
__global__ void fb_inv_kernel(const float* __restrict__ deg, float* __restrict__ inv, int N) {
    int i = blockIdx.x * blockDim.x + threadIdx.x;
    if (i < N) inv[i] = rsqrtf(1.0f + deg[i]);
}
__global__ void fb_scatter_kernel(const float* __restrict__ feat, const int* __restrict__ src,
                                  const int* __restrict__ dst, const float* __restrict__ inv,
                                  float* __restrict__ out, int E) {
    long long tid = (long long)blockIdx.x * blockDim.x + threadIdx.x;
    int e = (int)(tid >> 5);
    int d = (int)(tid & 31);
    if (e >= E) return;
    int s = src[e];
    int t = dst[e];
    atomicAdd(&out[t * D_FEAT + d], inv[s] * feat[s * D_FEAT + d]);
}
__global__ void fb_finalize_kernel(const float* __restrict__ feat, const float* __restrict__ inv,
                                   float* __restrict__ out, int ND) {
    int tid = blockIdx.x * blockDim.x + threadIdx.x;
    if (tid >= ND) return;
    float iv = inv[tid >> 5];
    out[tid] = iv * (out[tid] + iv * feat[tid]);
}

extern "C" void kernel_launch(void* const* d_in, const int* in_sizes, int n_in,
                              void* d_out, int out_size, void* d_ws, size_t ws_size,
                              hipStream_t stream) {
    const float* feat = (const float*)d_in[0];
    const int* esrc = (const int*)d_in[1];
    const int* edst = (const int*)d_in[2];
    float* out = (float*)d_out;

    const int N = in_sizes[0] / D_FEAT;
    const int E = in_sizes[1];
    const int ND = N * D_FEAT;
    const int NR = (N + RS_NODES - 1) >> RSH;
    const int chunk = (((E + NB_BIN - 1) / NB_BIN) + 3) & ~3;

    size_t wf_off = ((size_t)2 * E + 3) & ~(size_t)3;
    size_t after_rs = wf_off + 16 * (size_t)N + (size_t)NR * NB_BIN + (size_t)NR + (size_t)NR + 1;
    size_t ni_off = (after_rs + 1) & ~(size_t)1;  // 8B-align nodeinfo
    size_t need = (ni_off + 2 * ((size_t)N + 1)) * 4;
    if (ws_size >= need && NR <= MAX_NR && N <= (1 << LOCAL_SHIFT)) {
        unsigned* ws_u     = (unsigned*)d_ws;
        unsigned* binned   = ws_u;
        unsigned* csr      = binned + E;
        unsigned* wf       = ws_u + wf_off;
        unsigned* A        = wf + 16 * (size_t)N;
        unsigned* keytot   = A + (size_t)NR * NB_BIN;
        unsigned* rs       = keytot + NR;
        uint2*    ni       = (uint2*)(ws_u + ni_off);

        binA_kernel<<<NB_BIN, 256, 0, stream>>>(edst, A, E, NR, chunk);
        scanA_kernel<<<(NR + SCANA_TR - 1) / SCANA_TR, 512, 0, stream>>>(A, keytot, NR);
        scanR_kernel<<<1, 1024, 0, stream>>>(keytot, rs, NR);
        binB_kernel<<<NB_BIN, 256, 0, stream>>>(esrc, edst, A, rs, binned, E, NR, chunk);
        build_kernel<<<NR, RS_NODES, 0, stream>>>(binned, rs, feat, wf, csr, ni, N, E);
        {
            int total_waves = GATHER_BLOCKS * 4;
            int per = (N + total_waves - 1) / total_waves;
            gather_kernel<<<GATHER_BLOCKS, 256, 0, stream>>>(wf, csr, ni, out, N, per);
        }
    } else {
        float* deg = (float*)d_ws;
        float* inv = deg + N;
        hipMemsetAsync(deg, 0, (size_t)N * sizeof(float), stream);
        hipMemsetAsync(out, 0, (size_t)ND * sizeof(float), stream);
        {
            int grid = (E + 255) / 256; if (grid > 2048) grid = 2048;
            fb_deg_kernel<<<grid, 256, 0, stream>>>(edst, deg, E);
        }
        fb_inv_kernel<<<(N + 255) / 256, 256, 0, stream>>>(deg, inv, N);
        {
            long long total = (long long)E * D_FEAT;
            fb_scatter_kernel<<<(int)((total + 255) / 256), 256, 0, stream>>>(feat, esrc, edst, inv, out, E);
        }
        fb_finalize_kernel<<<(ND + 255) / 256, 256, 0, stream>>>(feat, inv, out, ND);
    }
}